// Round 1
// baseline (784.536 us; speedup 1.0000x reference)
//
#include <hip/hip_runtime.h>

#define B_   8
#define C_   256
#define TC_  512
#define HW_  2304   // 48*48
#define EPS_ 1e-6f

typedef __bf16 bf16_t;
typedef __bf16 bf16x8 __attribute__((ext_vector_type(8)));
typedef __bf16 bf16x4_t __attribute__((ext_vector_type(4)));
typedef float  f32x4 __attribute__((ext_vector_type(4)));

// ---------------------------------------------------------------------------
// 1x1 conv as per-batch GEMM: out[o][n] = sum_c W[o][c] * X[b][c][n]
// TRANS=true : write bf16 out[b][n][o]   (for q, k -> row-major [pixel][chan])
// TRANS=false: write bf16 out[b][o][n]   (for v -> [chan][pixel])
// Tile: 64 o x 64 n per block, 256 threads, each thread 4x4 outputs.
// ---------------------------------------------------------------------------
template<int CIN, bool TRANS>
__global__ __launch_bounds__(256)
void conv1x1_kernel(const float* __restrict__ W, const float* __restrict__ X,
                    bf16_t* __restrict__ out)
{
    const int n0 = blockIdx.x * 64;
    const int o0 = blockIdx.y * 64;
    const int b  = blockIdx.z;
    const float* Xb = X + (size_t)b * CIN * HW_;
    const int tid = threadIdx.x;
    const int tx = tid & 15;     // n sub-tile
    const int ty = tid >> 4;     // o sub-tile (0..15)

    __shared__ float Ws[16][64]; // [c][o]
    __shared__ float Xs[16][64]; // [c][n]

    float acc[4][4];
#pragma unroll
    for (int i = 0; i < 4; i++)
#pragma unroll
        for (int j = 0; j < 4; j++) acc[i][j] = 0.f;

    for (int c0 = 0; c0 < CIN; c0 += 16) {
        // stage W tile: 64 o x 16 c
        float4 wv = *(const float4*)(W + (size_t)(o0 + (tid & 63)) * CIN + c0 + (tid >> 6) * 4);
        {
            int o = tid & 63, cb = (tid >> 6) * 4;
            Ws[cb + 0][o] = wv.x; Ws[cb + 1][o] = wv.y;
            Ws[cb + 2][o] = wv.z; Ws[cb + 3][o] = wv.w;
        }
        // stage X tile: 16 c x 64 n (coalesced rows)
#pragma unroll
        for (int i = 0; i < 4; i++) {
            int cl = (tid >> 6) + i * 4;
            Xs[cl][tid & 63] = Xb[(size_t)(c0 + cl) * HW_ + n0 + (tid & 63)];
        }
        __syncthreads();
#pragma unroll
        for (int cc = 0; cc < 16; cc++) {
            float4 xv  = *(const float4*)&Xs[cc][tx * 4];
            float4 wv2 = *(const float4*)&Ws[cc][ty * 4];
            const float xr[4] = {xv.x, xv.y, xv.z, xv.w};
            const float wr[4] = {wv2.x, wv2.y, wv2.z, wv2.w};
#pragma unroll
            for (int oo = 0; oo < 4; oo++)
#pragma unroll
                for (int nn = 0; nn < 4; nn++)
                    acc[oo][nn] += wr[oo] * xr[nn];
        }
        __syncthreads();
    }

    if (TRANS) {
        // out[b][n][o], 4 consecutive o per store
#pragma unroll
        for (int nn = 0; nn < 4; nn++) {
            size_t n = (size_t)n0 + tx * 4 + nn;
            bf16_t* p = out + ((size_t)b * HW_ + n) * C_ + o0 + ty * 4;
            bf16x4_t vv;
            vv[0] = (__bf16)acc[0][nn]; vv[1] = (__bf16)acc[1][nn];
            vv[2] = (__bf16)acc[2][nn]; vv[3] = (__bf16)acc[3][nn];
            *(bf16x4_t*)p = vv;
        }
    } else {
        // out[b][o][n], 4 consecutive n per store
#pragma unroll
        for (int oo = 0; oo < 4; oo++) {
            bf16_t* p = out + ((size_t)b * C_ + o0 + ty * 4 + oo) * HW_ + n0 + tx * 4;
            bf16x4_t vv;
            vv[0] = (__bf16)acc[oo][0]; vv[1] = (__bf16)acc[oo][1];
            vv[2] = (__bf16)acc[oo][2]; vv[3] = (__bf16)acc[oo][3];
            *(bf16x4_t*)p = vv;
        }
    }
}

// ---------------------------------------------------------------------------
// In-place L2-normalize each 256-length row of a [B*N][C] bf16 buffer.
// One wave per pixel, 4 bf16 per lane.
// ---------------------------------------------------------------------------
__global__ __launch_bounds__(256)
void norm_kernel(bf16_t* __restrict__ q)
{
    const int pix  = blockIdx.x * 4 + (threadIdx.x >> 6);
    const int lane = threadIdx.x & 63;
    bf16_t* p = q + (size_t)pix * C_ + lane * 4;
    bf16x4_t v = *(const bf16x4_t*)p;
    float f0 = (float)v[0], f1 = (float)v[1], f2 = (float)v[2], f3 = (float)v[3];
    float ss = f0 * f0 + f1 * f1 + f2 * f2 + f3 * f3;
    ss += __shfl_xor(ss, 1);
    ss += __shfl_xor(ss, 2);
    ss += __shfl_xor(ss, 4);
    ss += __shfl_xor(ss, 8);
    ss += __shfl_xor(ss, 16);
    ss += __shfl_xor(ss, 32);
    float scale = 1.0f / fmaxf(sqrtf(ss), EPS_);
    v[0] = (__bf16)(f0 * scale); v[1] = (__bf16)(f1 * scale);
    v[2] = (__bf16)(f2 * scale); v[3] = (__bf16)(f3 * scale);
    *(bf16x4_t*)p = v;
}

// ---------------------------------------------------------------------------
// Attention: out[b][c][n] = x[b][c][n] + alpha * (sum_j exp(s_nj) * v[c][j]) / sum_j exp(s_nj)
// s_nj = (qn[n]·kn[j]) / 16.  Logits bounded by 1/16 -> no max subtraction.
// qn,kn: bf16 [B][N][C] row-major.  v: bf16 [B][C][N].
// Block = 4 waves; wave w owns 16 Q rows; loops over all 2304 cols in 32-tiles.
// ---------------------------------------------------------------------------
__global__ __launch_bounds__(256)
void attn_kernel(const bf16_t* __restrict__ qn, const bf16_t* __restrict__ kn,
                 const bf16_t* __restrict__ v,  const float* __restrict__ x,
                 const float* __restrict__ alphaPtr, float* __restrict__ out)
{
    const int b    = blockIdx.y;
    const int wave = threadIdx.x >> 6;
    const int lane = threadIdx.x & 63;
    const int quad = lane >> 4;    // 0..3
    const int l16  = lane & 15;
    const int row0 = blockIdx.x * 64 + wave * 16;  // first Q row of this wave

    const bf16_t* qb = qn + (size_t)b * HW_ * C_;
    const bf16_t* kb = kn + (size_t)b * HW_ * C_;
    const bf16_t* vb = v  + (size_t)b * C_ * HW_;

    // Q fragments: A[m=l16][k = t*32 + quad*8 + i]
    bf16x8 aq[8];
    {
        const bf16_t* qrow = qb + (size_t)(row0 + l16) * C_ + quad * 8;
#pragma unroll
        for (int t = 0; t < 8; t++) aq[t] = *(const bf16x8*)(qrow + t * 32);
    }

    f32x4 O[16];
#pragma unroll
    for (int i = 0; i < 16; i++) O[i] = (f32x4){0.f, 0.f, 0.f, 0.f};
    float lsum[4] = {0.f, 0.f, 0.f, 0.f};

    // per-wave P tile (16 rows x 32 cols), row stride 40 bf16 to dodge conflicts
    __shared__ bf16_t Pt[4][16 * 40];
    bf16_t* pw = &Pt[wave][0];

    for (int j0 = 0; j0 < HW_; j0 += 32) {
        f32x4 s0 = (f32x4){0.f, 0.f, 0.f, 0.f};
        f32x4 s1 = (f32x4){0.f, 0.f, 0.f, 0.f};
        const bf16_t* krow0 = kb + (size_t)(j0 + l16) * C_ + quad * 8;
        const bf16_t* krow1 = krow0 + 16 * C_;
#pragma unroll
        for (int t = 0; t < 8; t++) {
            bf16x8 bk0 = *(const bf16x8*)(krow0 + t * 32);
            bf16x8 bk1 = *(const bf16x8*)(krow1 + t * 32);
            s0 = __builtin_amdgcn_mfma_f32_16x16x32_bf16(aq[t], bk0, s0, 0, 0, 0);
            s1 = __builtin_amdgcn_mfma_f32_16x16x32_bf16(aq[t], bk1, s1, 0, 0, 0);
        }
        // exp (logits in [-1/16, 1/16], no max needed)
        float p0[4], p1[4];
#pragma unroll
        for (int r = 0; r < 4; r++) {
            p0[r] = __expf(s0[r] * 0.0625f);
            p1[r] = __expf(s1[r] * 0.0625f);
        }
        // row sums: butterfly across the 16-lane col groups
#pragma unroll
        for (int r = 0; r < 4; r++) {
            float t = p0[r] + p1[r];
            t += __shfl_xor(t, 1);
            t += __shfl_xor(t, 2);
            t += __shfl_xor(t, 4);
            t += __shfl_xor(t, 8);
            lsum[r] += t;
        }
        // P (C/D layout: row=quad*4+r, col=l16) -> LDS row-major
#pragma unroll
        for (int r = 0; r < 4; r++) {
            pw[(quad * 4 + r) * 40 + l16]      = (__bf16)p0[r];
            pw[(quad * 4 + r) * 40 + 16 + l16] = (__bf16)p1[r];
        }
        // read back as A operand: A[m=l16][k=quad*8+i]
        bf16x8 ap = *(const bf16x8*)(pw + l16 * 40 + quad * 8);
        // P·V: B[k=j][n=c] from v[c][j] rows (contiguous)
#pragma unroll
        for (int ct = 0; ct < 16; ct++) {
            const bf16_t* vrow = vb + (size_t)(ct * 16 + l16) * HW_ + j0 + quad * 8;
            bf16x8 bv = *(const bf16x8*)vrow;
            O[ct] = __builtin_amdgcn_mfma_f32_16x16x32_bf16(ap, bv, O[ct], 0, 0, 0);
        }
    }

    // epilogue: out[b][c][n] = x + alpha * O/lsum ; D layout row=n offset, col=c
    const float a = *alphaPtr;
    float il[4];
#pragma unroll
    for (int r = 0; r < 4; r++) il[r] = 1.0f / lsum[r];

    const float* xb = x   + (size_t)b * C_ * HW_;
    float*       ob = out + (size_t)b * C_ * HW_;
#pragma unroll
    for (int ct = 0; ct < 16; ct++) {
        int c = ct * 16 + l16;
        size_t base = (size_t)c * HW_ + row0 + quad * 4;
        float4 xv = *(const float4*)(xb + base);
        float4 r;
        r.x = xv.x + a * O[ct][0] * il[0];
        r.y = xv.y + a * O[ct][1] * il[1];
        r.z = xv.z + a * O[ct][2] * il[2];
        r.w = xv.w + a * O[ct][3] * il[3];
        *(float4*)(ob + base) = r;
    }
}

// ---------------------------------------------------------------------------
extern "C" void kernel_launch(void* const* d_in, const int* in_sizes, int n_in,
                              void* d_out, int out_size, void* d_ws, size_t ws_size,
                              hipStream_t stream)
{
    (void)in_sizes; (void)n_in; (void)out_size; (void)ws_size;
    const float* x     = (const float*)d_in[0];
    const float* token = (const float*)d_in[1];
    const float* Wq    = (const float*)d_in[2];
    const float* Wk    = (const float*)d_in[3];
    const float* Wv    = (const float*)d_in[4];
    const float* alpha = (const float*)d_in[5];
    float* out = (float*)d_out;

    const size_t S = (size_t)B_ * HW_ * C_;   // elements per bf16 buffer
    bf16_t* qb = (bf16_t*)d_ws;               // [B][N][C]
    bf16_t* kb = qb + S;                      // [B][N][C]
    bf16_t* vb = kb + S;                      // [B][C][N]

    dim3 blk(256);
    conv1x1_kernel<C_,  true ><<<dim3(HW_ / 64, C_ / 64, B_), blk, 0, stream>>>(Wq, x,     qb);
    conv1x1_kernel<TC_, true ><<<dim3(HW_ / 64, C_ / 64, B_), blk, 0, stream>>>(Wk, token, kb);
    conv1x1_kernel<TC_, false><<<dim3(HW_ / 64, C_ / 64, B_), blk, 0, stream>>>(Wv, token, vb);
    norm_kernel<<<dim3(B_ * HW_ / 4), blk, 0, stream>>>(qb);
    norm_kernel<<<dim3(B_ * HW_ / 4), blk, 0, stream>>>(kb);
    attn_kernel<<<dim3(HW_ / 64, B_), blk, 0, stream>>>(qb, kb, vb, x, alpha, out);
}

// Round 2
// 595.740 us; speedup vs baseline: 1.3169x; 1.3169x over previous
//
#include <hip/hip_runtime.h>

#define B_   8
#define C_   256
#define TC_  512
#define HW_  2304   // 48*48
#define EPS_ 1e-6f

typedef __bf16 bf16_t;
typedef __bf16 bf16x8 __attribute__((ext_vector_type(8)));
typedef __bf16 bf16x4_t __attribute__((ext_vector_type(4)));
typedef float  f32x4 __attribute__((ext_vector_type(4)));

// ---------------------------------------------------------------------------
// Transpose + cast: X [B][CIN][HW] fp32 -> XT [B][HW][CIN] bf16.  64x64 tiles.
// ---------------------------------------------------------------------------
template<int CIN>
__global__ __launch_bounds__(256)
void transpose_cast_kernel(const float* __restrict__ X, bf16_t* __restrict__ XT)
{
    const int n0 = blockIdx.x * 64;
    const int c0 = blockIdx.y * 64;
    const int b  = blockIdx.z;
    const int tid = threadIdx.x;
    __shared__ bf16_t T[64][72];  // [n][c], pad 72 keeps rows 16B-aligned

    const float* Xb = X + ((size_t)b * CIN + c0) * HW_ + n0;
    {
        int cl = tid >> 4;          // 0..15
        int nl = (tid & 15) * 4;    // 0..60
#pragma unroll
        for (int p = 0; p < 4; p++) {
            float4 v = *(const float4*)(Xb + (size_t)(cl + p * 16) * HW_ + nl);
            T[nl + 0][cl + p * 16] = (__bf16)v.x;
            T[nl + 1][cl + p * 16] = (__bf16)v.y;
            T[nl + 2][cl + p * 16] = (__bf16)v.z;
            T[nl + 3][cl + p * 16] = (__bf16)v.w;
        }
    }
    __syncthreads();
    bf16_t* Ob = XT + ((size_t)b * HW_ + n0) * CIN + c0;
    {
        int nl = tid >> 4;
        int cl = (tid & 15) * 4;
#pragma unroll
        for (int p = 0; p < 4; p++) {
            bf16x4_t v;
            v[0] = T[nl + p * 16][cl + 0]; v[1] = T[nl + p * 16][cl + 1];
            v[2] = T[nl + p * 16][cl + 2]; v[3] = T[nl + p * 16][cl + 3];
            *(bf16x4_t*)(Ob + (size_t)(nl + p * 16) * CIN + cl) = v;
        }
    }
}

// ---------------------------------------------------------------------------
// MFMA conv (TRANS output): out[b][n][o] = sum_c W[o][c] * XT[b][n][c]
// A = pixels (m), B = W rows (n=o).  Block: 64 pixels x 64 o, wave -> o-sub.
// ---------------------------------------------------------------------------
template<int CIN>
__global__ __launch_bounds__(256)
void convT_kernel(const bf16_t* __restrict__ XT, const float* __restrict__ W,
                  bf16_t* __restrict__ out)
{
    const int n0 = blockIdx.x * 64;
    const int o0 = blockIdx.y * 64;
    const int b  = blockIdx.z;
    const int wv = threadIdx.x >> 6;
    const int lane = threadIdx.x & 63;
    const int quad = lane >> 4, l16 = lane & 15;

    const bf16_t* Xb = XT + ((size_t)b * HW_ + n0) * CIN;
    const float*  Wr = W + (size_t)(o0 + wv * 16 + l16) * CIN + quad * 8;

    f32x4 acc[4];
#pragma unroll
    for (int f = 0; f < 4; f++) acc[f] = (f32x4){0.f, 0.f, 0.f, 0.f};

    for (int c0 = 0; c0 < CIN; c0 += 32) {
        float4 w0 = *(const float4*)(Wr + c0);
        float4 w1 = *(const float4*)(Wr + c0 + 4);
        bf16x8 bw;
        bw[0] = (__bf16)w0.x; bw[1] = (__bf16)w0.y; bw[2] = (__bf16)w0.z; bw[3] = (__bf16)w0.w;
        bw[4] = (__bf16)w1.x; bw[5] = (__bf16)w1.y; bw[6] = (__bf16)w1.z; bw[7] = (__bf16)w1.w;
#pragma unroll
        for (int f = 0; f < 4; f++) {
            bf16x8 av = *(const bf16x8*)(Xb + (size_t)(f * 16 + l16) * CIN + c0 + quad * 8);
            acc[f] = __builtin_amdgcn_mfma_f32_16x16x32_bf16(av, bw, acc[f], 0, 0, 0);
        }
    }
    // D: row = pixel = f*16+quad*4+r, col = o = o0+wv*16+l16
    bf16_t* Ob = out + ((size_t)b * HW_ + n0) * C_ + o0 + wv * 16 + l16;
#pragma unroll
    for (int f = 0; f < 4; f++)
#pragma unroll
        for (int r = 0; r < 4; r++)
            Ob[(size_t)(f * 16 + quad * 4 + r) * C_] = (__bf16)acc[f][r];
}

// ---------------------------------------------------------------------------
// MFMA conv (plain output): out[b][o][n] = sum_c W[o][c] * XT[b][n][c]
// A = W rows (m=o), B = pixels (n).  Same loads as convT, swapped roles.
// ---------------------------------------------------------------------------
template<int CIN>
__global__ __launch_bounds__(256)
void convV_kernel(const bf16_t* __restrict__ XT, const float* __restrict__ W,
                  bf16_t* __restrict__ out)
{
    const int n0 = blockIdx.x * 64;
    const int o0 = blockIdx.y * 64;
    const int b  = blockIdx.z;
    const int wv = threadIdx.x >> 6;
    const int lane = threadIdx.x & 63;
    const int quad = lane >> 4, l16 = lane & 15;

    const bf16_t* Xb = XT + ((size_t)b * HW_ + n0) * CIN;
    const float*  Wr = W + (size_t)(o0 + wv * 16 + l16) * CIN + quad * 8;

    f32x4 acc[4];
#pragma unroll
    for (int f = 0; f < 4; f++) acc[f] = (f32x4){0.f, 0.f, 0.f, 0.f};

    for (int c0 = 0; c0 < CIN; c0 += 32) {
        float4 w0 = *(const float4*)(Wr + c0);
        float4 w1 = *(const float4*)(Wr + c0 + 4);
        bf16x8 aw;
        aw[0] = (__bf16)w0.x; aw[1] = (__bf16)w0.y; aw[2] = (__bf16)w0.z; aw[3] = (__bf16)w0.w;
        aw[4] = (__bf16)w1.x; aw[5] = (__bf16)w1.y; aw[6] = (__bf16)w1.z; aw[7] = (__bf16)w1.w;
#pragma unroll
        for (int f = 0; f < 4; f++) {
            bf16x8 bv = *(const bf16x8*)(Xb + (size_t)(f * 16 + l16) * CIN + c0 + quad * 8);
            acc[f] = __builtin_amdgcn_mfma_f32_16x16x32_bf16(aw, bv, acc[f], 0, 0, 0);
        }
    }
    // D: row = o = o0+wv*16+quad*4+r, col = pixel = n0+f*16+l16
#pragma unroll
    for (int r = 0; r < 4; r++) {
        bf16_t* Ob = out + ((size_t)b * C_ + o0 + wv * 16 + quad * 4 + r) * HW_ + n0 + l16;
#pragma unroll
        for (int f = 0; f < 4; f++)
            Ob[f * 16] = (__bf16)acc[f][r];
    }
}

// ---------------------------------------------------------------------------
// In-place L2-normalize each 256-length row of a [B*N][C] bf16 buffer.
// ---------------------------------------------------------------------------
__global__ __launch_bounds__(256)
void norm_kernel(bf16_t* __restrict__ q)
{
    const int pix  = blockIdx.x * 4 + (threadIdx.x >> 6);
    const int lane = threadIdx.x & 63;
    bf16_t* p = q + (size_t)pix * C_ + lane * 4;
    bf16x4_t v = *(const bf16x4_t*)p;
    float f0 = (float)v[0], f1 = (float)v[1], f2 = (float)v[2], f3 = (float)v[3];
    float ss = f0 * f0 + f1 * f1 + f2 * f2 + f3 * f3;
    ss += __shfl_xor(ss, 1);
    ss += __shfl_xor(ss, 2);
    ss += __shfl_xor(ss, 4);
    ss += __shfl_xor(ss, 8);
    ss += __shfl_xor(ss, 16);
    ss += __shfl_xor(ss, 32);
    float scale = 1.0f / fmaxf(sqrtf(ss), EPS_);
    v[0] = (__bf16)(f0 * scale); v[1] = (__bf16)(f1 * scale);
    v[2] = (__bf16)(f2 * scale); v[3] = (__bf16)(f3 * scale);
    *(bf16x4_t*)p = v;
}

// ---------------------------------------------------------------------------
// Attention partials over a column split.  Logits in [-1/16,1/16] -> exp
// without max; numerator and denominator are linear in j -> slab reduce.
// Opart: bf16 [js][b][c][n]; lpart: fp32 [js][b][n].
// ---------------------------------------------------------------------------
__global__ __launch_bounds__(256)
void attn_part_kernel(const bf16_t* __restrict__ qn, const bf16_t* __restrict__ kn,
                      const bf16_t* __restrict__ v,
                      bf16_t* __restrict__ Opart, float* __restrict__ lpart,
                      int tilesPerSplit)
{
    const int b    = blockIdx.z;
    const int js   = blockIdx.y;
    const int wave = threadIdx.x >> 6;
    const int lane = threadIdx.x & 63;
    const int quad = lane >> 4;
    const int l16  = lane & 15;
    const int row0 = blockIdx.x * 64 + wave * 16;
    const int jbase = js * tilesPerSplit * 32;

    const bf16_t* qb = qn + (size_t)b * HW_ * C_;
    const bf16_t* kb = kn + (size_t)b * HW_ * C_;
    const bf16_t* vb = v  + (size_t)b * C_ * HW_;

    bf16x8 aq[8];
    {
        const bf16_t* qrow = qb + (size_t)(row0 + l16) * C_ + quad * 8;
#pragma unroll
        for (int t = 0; t < 8; t++) aq[t] = *(const bf16x8*)(qrow + t * 32);
    }

    f32x4 O[16];
#pragma unroll
    for (int i = 0; i < 16; i++) O[i] = (f32x4){0.f, 0.f, 0.f, 0.f};
    float lsum[4] = {0.f, 0.f, 0.f, 0.f};

    __shared__ bf16_t Pt[4][16 * 40];
    bf16_t* pw = &Pt[wave][0];

    for (int tt = 0; tt < tilesPerSplit; tt++) {
        const int j0 = jbase + tt * 32;
        f32x4 s0 = (f32x4){0.f, 0.f, 0.f, 0.f};
        f32x4 s1 = (f32x4){0.f, 0.f, 0.f, 0.f};
        const bf16_t* krow0 = kb + (size_t)(j0 + l16) * C_ + quad * 8;
        const bf16_t* krow1 = krow0 + 16 * C_;
#pragma unroll
        for (int t = 0; t < 8; t++) {
            bf16x8 bk0 = *(const bf16x8*)(krow0 + t * 32);
            bf16x8 bk1 = *(const bf16x8*)(krow1 + t * 32);
            s0 = __builtin_amdgcn_mfma_f32_16x16x32_bf16(aq[t], bk0, s0, 0, 0, 0);
            s1 = __builtin_amdgcn_mfma_f32_16x16x32_bf16(aq[t], bk1, s1, 0, 0, 0);
        }
        float p0[4], p1[4];
#pragma unroll
        for (int r = 0; r < 4; r++) {
            p0[r] = __expf(s0[r] * 0.0625f);
            p1[r] = __expf(s1[r] * 0.0625f);
        }
#pragma unroll
        for (int r = 0; r < 4; r++) {
            float t = p0[r] + p1[r];
            t += __shfl_xor(t, 1);
            t += __shfl_xor(t, 2);
            t += __shfl_xor(t, 4);
            t += __shfl_xor(t, 8);
            lsum[r] += t;
        }
#pragma unroll
        for (int r = 0; r < 4; r++) {
            pw[(quad * 4 + r) * 40 + l16]      = (__bf16)p0[r];
            pw[(quad * 4 + r) * 40 + 16 + l16] = (__bf16)p1[r];
        }
        bf16x8 ap = *(const bf16x8*)(pw + l16 * 40 + quad * 8);
#pragma unroll
        for (int ct = 0; ct < 16; ct++) {
            const bf16_t* vrow = vb + (size_t)(ct * 16 + l16) * HW_ + j0 + quad * 8;
            bf16x8 bv = *(const bf16x8*)vrow;
            O[ct] = __builtin_amdgcn_mfma_f32_16x16x32_bf16(ap, bv, O[ct], 0, 0, 0);
        }
    }

    // store partials
    float* lp = lpart + (size_t)(js * B_ + b) * HW_;
    if (l16 == 0) {
        float4 lv; lv.x = lsum[0]; lv.y = lsum[1]; lv.z = lsum[2]; lv.w = lsum[3];
        *(float4*)(lp + row0 + quad * 4) = lv;
    }
    bf16_t* op = Opart + (size_t)(js * B_ + b) * C_ * HW_;
#pragma unroll
    for (int ct = 0; ct < 16; ct++) {
        int c = ct * 16 + l16;
        bf16x4_t vv;
        vv[0] = (__bf16)O[ct][0]; vv[1] = (__bf16)O[ct][1];
        vv[2] = (__bf16)O[ct][2]; vv[3] = (__bf16)O[ct][3];
        *(bf16x4_t*)(op + (size_t)c * HW_ + row0 + quad * 4) = vv;
    }
}

// ---------------------------------------------------------------------------
__global__ __launch_bounds__(256)
void lsum_combine_kernel(const float* __restrict__ lpart, float* __restrict__ linv, int JS)
{
    int i = blockIdx.x * 256 + threadIdx.x;   // 0 .. B*HW-1
    float s = 0.f;
    for (int js = 0; js < JS; js++) s += lpart[(size_t)js * B_ * HW_ + i];
    linv[i] = 1.0f / s;
}

// out[b][c][n] = x + alpha * (sum_js Opart) * linv[b][n]
__global__ __launch_bounds__(256)
void epilogue_kernel(const float* __restrict__ x, const bf16_t* __restrict__ Opart,
                     const float* __restrict__ linv, const float* __restrict__ alphaPtr,
                     float* __restrict__ out, int JS)
{
    const float a = *alphaPtr;
    const size_t S = (size_t)B_ * C_ * HW_;
    size_t flat = ((size_t)blockIdx.x * 256 + threadIdx.x) * 4;
    int bc = (int)(flat / HW_);
    int n  = (int)(flat % HW_);
    int b  = bc >> 8;
    float4 xv = *(const float4*)(x + flat);
    float s0 = 0.f, s1 = 0.f, s2 = 0.f, s3 = 0.f;
    for (int js = 0; js < JS; js++) {
        bf16x4_t ov = *(const bf16x4_t*)(Opart + (size_t)js * S + flat);
        s0 += (float)ov[0]; s1 += (float)ov[1];
        s2 += (float)ov[2]; s3 += (float)ov[3];
    }
    float4 lv = *(const float4*)(linv + (size_t)b * HW_ + n);
    float4 r;
    r.x = xv.x + a * s0 * lv.x;
    r.y = xv.y + a * s1 * lv.y;
    r.z = xv.z + a * s2 * lv.z;
    r.w = xv.w + a * s3 * lv.w;
    *(float4*)(out + flat) = r;
}

// ---------------------------------------------------------------------------
extern "C" void kernel_launch(void* const* d_in, const int* in_sizes, int n_in,
                              void* d_out, int out_size, void* d_ws, size_t ws_size,
                              hipStream_t stream)
{
    (void)in_sizes; (void)n_in; (void)out_size;
    const float* x     = (const float*)d_in[0];
    const float* token = (const float*)d_in[1];
    const float* Wq    = (const float*)d_in[2];
    const float* Wk    = (const float*)d_in[3];
    const float* Wv    = (const float*)d_in[4];
    const float* alpha = (const float*)d_in[5];
    float* out = (float*)d_out;

    const size_t S = (size_t)B_ * HW_ * C_;   // 4,718,592 elements

    // pick largest column-split that fits the workspace
    int JS = 4;
    for (;;) {
        size_t need = (12 + 2 * (size_t)JS) * S
                    + (size_t)JS * B_ * HW_ * 4 + (size_t)B_ * HW_ * 4;
        if (need <= ws_size || JS == 1) break;
        JS >>= 1;
    }
    const int tilesPerSplit = (HW_ / 32) / JS;  // 72/JS

    char* ws = (char*)d_ws;
    bf16_t* qb    = (bf16_t*)(ws);                       // [b][n][C]
    bf16_t* kb    = (bf16_t*)(ws + 2 * S);               // [b][n][C]
    bf16_t* vb    = (bf16_t*)(ws + 4 * S);               // [b][C][n]
    bf16_t* xT    = (bf16_t*)(ws + 6 * S);               // [b][n][C]
    bf16_t* tT    = (bf16_t*)(ws + 8 * S);               // [b][n][TC]
    bf16_t* Opart = (bf16_t*)(ws + 12 * S);              // [js][b][c][n]
    float*  lpart = (float*)(ws + (12 + 2 * (size_t)JS) * S);
    float*  linv  = lpart + (size_t)JS * B_ * HW_;

    dim3 blk(256);
    transpose_cast_kernel<C_ ><<<dim3(HW_ / 64, C_  / 64, B_), blk, 0, stream>>>(x,     xT);
    transpose_cast_kernel<TC_><<<dim3(HW_ / 64, TC_ / 64, B_), blk, 0, stream>>>(token, tT);
    convT_kernel<C_ ><<<dim3(HW_ / 64, C_ / 64, B_), blk, 0, stream>>>(xT, Wq, qb);
    convT_kernel<TC_><<<dim3(HW_ / 64, C_ / 64, B_), blk, 0, stream>>>(tT, Wk, kb);
    convV_kernel<TC_><<<dim3(HW_ / 64, C_ / 64, B_), blk, 0, stream>>>(tT, Wv, vb);
    norm_kernel<<<dim3(B_ * HW_ / 4), blk, 0, stream>>>(qb);
    norm_kernel<<<dim3(B_ * HW_ / 4), blk, 0, stream>>>(kb);
    attn_part_kernel<<<dim3(HW_ / 64, JS, B_), blk, 0, stream>>>(qb, kb, vb, Opart, lpart, tilesPerSplit);
    lsum_combine_kernel<<<dim3(B_ * HW_ / 256), blk, 0, stream>>>(lpart, linv, JS);
    epilogue_kernel<<<dim3((int)(S / 1024)), blk, 0, stream>>>(x, Opart, linv, alpha, out, JS);
}

// Round 3
// 392.507 us; speedup vs baseline: 1.9988x; 1.5178x over previous
//
#include <hip/hip_runtime.h>

#define B_   8
#define C_   256
#define TC_  512
#define HW_  2304   // 48*48
#define EPS_ 1e-6f

typedef __bf16 bf16_t;
typedef __bf16 bf16x8 __attribute__((ext_vector_type(8)));
typedef __bf16 bf16x4_t __attribute__((ext_vector_type(4)));
typedef float  f32x4 __attribute__((ext_vector_type(4)));

// async 16B global->LDS; lds base must be wave-uniform (lane i lands at base+16i)
__device__ __forceinline__ void g2l16(const bf16_t* g, bf16_t* l) {
    __builtin_amdgcn_global_load_lds(
        (const __attribute__((address_space(1))) unsigned int*)g,
        (__attribute__((address_space(3))) unsigned int*)l, 16, 0, 0);
}

// ---------------------------------------------------------------------------
// Transpose + cast: X [B][CIN][HW] fp32 -> XT [B][HW][CIN] bf16.  64x64 tiles.
// ---------------------------------------------------------------------------
template<int CIN>
__global__ __launch_bounds__(256)
void transpose_cast_kernel(const float* __restrict__ X, bf16_t* __restrict__ XT)
{
    const int n0 = blockIdx.x * 64;
    const int c0 = blockIdx.y * 64;
    const int b  = blockIdx.z;
    const int tid = threadIdx.x;
    __shared__ bf16_t T[64][72];

    const float* Xb = X + ((size_t)b * CIN + c0) * HW_ + n0;
    {
        int cl = tid >> 4;
        int nl = (tid & 15) * 4;
#pragma unroll
        for (int p = 0; p < 4; p++) {
            float4 v = *(const float4*)(Xb + (size_t)(cl + p * 16) * HW_ + nl);
            T[nl + 0][cl + p * 16] = (__bf16)v.x;
            T[nl + 1][cl + p * 16] = (__bf16)v.y;
            T[nl + 2][cl + p * 16] = (__bf16)v.z;
            T[nl + 3][cl + p * 16] = (__bf16)v.w;
        }
    }
    __syncthreads();
    bf16_t* Ob = XT + ((size_t)b * HW_ + n0) * CIN + c0;
    {
        int nl = tid >> 4;
        int cl = (tid & 15) * 4;
#pragma unroll
        for (int p = 0; p < 4; p++) {
            bf16x4_t v;
            v[0] = T[nl + p * 16][cl + 0]; v[1] = T[nl + p * 16][cl + 1];
            v[2] = T[nl + p * 16][cl + 2]; v[3] = T[nl + p * 16][cl + 3];
            *(bf16x4_t*)(Ob + (size_t)(nl + p * 16) * CIN + cl) = v;
        }
    }
}

// ---------------------------------------------------------------------------
// MFMA conv (TRANS output): out[b][n][o] = sum_c W[o][c] * XT[b][n][c]
// ---------------------------------------------------------------------------
template<int CIN>
__global__ __launch_bounds__(256)
void convT_kernel(const bf16_t* __restrict__ XT, const float* __restrict__ W,
                  bf16_t* __restrict__ out)
{
    const int n0 = blockIdx.x * 64;
    const int o0 = blockIdx.y * 64;
    const int b  = blockIdx.z;
    const int wv = threadIdx.x >> 6;
    const int lane = threadIdx.x & 63;
    const int quad = lane >> 4, l16 = lane & 15;

    const bf16_t* Xb = XT + ((size_t)b * HW_ + n0) * CIN;
    const float*  Wr = W + (size_t)(o0 + wv * 16 + l16) * CIN + quad * 8;

    f32x4 acc[4];
#pragma unroll
    for (int f = 0; f < 4; f++) acc[f] = (f32x4){0.f, 0.f, 0.f, 0.f};

    for (int c0 = 0; c0 < CIN; c0 += 32) {
        float4 w0 = *(const float4*)(Wr + c0);
        float4 w1 = *(const float4*)(Wr + c0 + 4);
        bf16x8 bw;
        bw[0] = (__bf16)w0.x; bw[1] = (__bf16)w0.y; bw[2] = (__bf16)w0.z; bw[3] = (__bf16)w0.w;
        bw[4] = (__bf16)w1.x; bw[5] = (__bf16)w1.y; bw[6] = (__bf16)w1.z; bw[7] = (__bf16)w1.w;
#pragma unroll
        for (int f = 0; f < 4; f++) {
            bf16x8 av = *(const bf16x8*)(Xb + (size_t)(f * 16 + l16) * CIN + c0 + quad * 8);
            acc[f] = __builtin_amdgcn_mfma_f32_16x16x32_bf16(av, bw, acc[f], 0, 0, 0);
        }
    }
    bf16_t* Ob = out + ((size_t)b * HW_ + n0) * C_ + o0 + wv * 16 + l16;
#pragma unroll
    for (int f = 0; f < 4; f++)
#pragma unroll
        for (int r = 0; r < 4; r++)
            Ob[(size_t)(f * 16 + quad * 4 + r) * C_] = (__bf16)acc[f][r];
}

// ---------------------------------------------------------------------------
// MFMA conv (plain output): out[b][o][n]
// ---------------------------------------------------------------------------
template<int CIN>
__global__ __launch_bounds__(256)
void convV_kernel(const bf16_t* __restrict__ XT, const float* __restrict__ W,
                  bf16_t* __restrict__ out)
{
    const int n0 = blockIdx.x * 64;
    const int o0 = blockIdx.y * 64;
    const int b  = blockIdx.z;
    const int wv = threadIdx.x >> 6;
    const int lane = threadIdx.x & 63;
    const int quad = lane >> 4, l16 = lane & 15;

    const bf16_t* Xb = XT + ((size_t)b * HW_ + n0) * CIN;
    const float*  Wr = W + (size_t)(o0 + wv * 16 + l16) * CIN + quad * 8;

    f32x4 acc[4];
#pragma unroll
    for (int f = 0; f < 4; f++) acc[f] = (f32x4){0.f, 0.f, 0.f, 0.f};

    for (int c0 = 0; c0 < CIN; c0 += 32) {
        float4 w0 = *(const float4*)(Wr + c0);
        float4 w1 = *(const float4*)(Wr + c0 + 4);
        bf16x8 aw;
        aw[0] = (__bf16)w0.x; aw[1] = (__bf16)w0.y; aw[2] = (__bf16)w0.z; aw[3] = (__bf16)w0.w;
        aw[4] = (__bf16)w1.x; aw[5] = (__bf16)w1.y; aw[6] = (__bf16)w1.z; aw[7] = (__bf16)w1.w;
#pragma unroll
        for (int f = 0; f < 4; f++) {
            bf16x8 bv = *(const bf16x8*)(Xb + (size_t)(f * 16 + l16) * CIN + c0 + quad * 8);
            acc[f] = __builtin_amdgcn_mfma_f32_16x16x32_bf16(aw, bv, acc[f], 0, 0, 0);
        }
    }
#pragma unroll
    for (int r = 0; r < 4; r++) {
        bf16_t* Ob = out + ((size_t)b * C_ + o0 + wv * 16 + quad * 4 + r) * HW_ + n0 + l16;
#pragma unroll
        for (int f = 0; f < 4; f++)
            Ob[f * 16] = (__bf16)acc[f][r];
    }
}

// ---------------------------------------------------------------------------
__global__ __launch_bounds__(256)
void norm_kernel(bf16_t* __restrict__ q)
{
    const int pix  = blockIdx.x * 4 + (threadIdx.x >> 6);
    const int lane = threadIdx.x & 63;
    bf16_t* p = q + (size_t)pix * C_ + lane * 4;
    bf16x4_t v = *(const bf16x4_t*)p;
    float f0 = (float)v[0], f1 = (float)v[1], f2 = (float)v[2], f3 = (float)v[3];
    float ss = f0 * f0 + f1 * f1 + f2 * f2 + f3 * f3;
    ss += __shfl_xor(ss, 1);
    ss += __shfl_xor(ss, 2);
    ss += __shfl_xor(ss, 4);
    ss += __shfl_xor(ss, 8);
    ss += __shfl_xor(ss, 16);
    ss += __shfl_xor(ss, 32);
    float scale = 1.0f / fmaxf(sqrtf(ss), EPS_);
    v[0] = (__bf16)(f0 * scale); v[1] = (__bf16)(f1 * scale);
    v[2] = (__bf16)(f2 * scale); v[3] = (__bf16)(f3 * scale);
    *(bf16x4_t*)p = v;
}

// ---------------------------------------------------------------------------
// Attention partials, LDS-staged K/V (double-buffered, swizzled), 2 m-tiles
// per wave (128 Q rows / block).  Per-lane lsum, reduced once at the end.
// K LDS: row j (32 rows x 512B), chunk s holds global chunk s^(j&7).
// V LDS: row c (256 rows x 64B),  chunk s holds global chunk s^(c&3).
// ---------------------------------------------------------------------------
__global__ __launch_bounds__(256, 2)
void attn_part_kernel(const bf16_t* __restrict__ qn, const bf16_t* __restrict__ kn,
                      const bf16_t* __restrict__ v,
                      bf16_t* __restrict__ Opart, float* __restrict__ lpart,
                      int tilesPerSplit)
{
    const int b    = blockIdx.z;
    const int js   = blockIdx.y;
    const int wv   = threadIdx.x >> 6;
    const int lane = threadIdx.x & 63;
    const int quad = lane >> 4;
    const int l16  = lane & 15;
    const int row0 = blockIdx.x * 128 + wv * 32;     // wave owns rows row0..row0+31
    const int jbase = js * tilesPerSplit * 32;

    const bf16_t* qb = qn + (size_t)b * HW_ * C_;
    const bf16_t* kb = kn + (size_t)b * HW_ * C_;
    const bf16_t* vb = v  + (size_t)b * C_ * HW_;

    __shared__ bf16_t Kbuf[2][32 * 256];   // 16 KB each
    __shared__ bf16_t Vbuf[2][256 * 32];   // 16 KB each
    __shared__ bf16_t Pt[4][2 * 16 * 40];  // per-wave P, 2 m-tiles

    // Q fragments for both m-tiles
    bf16x8 aq0[8], aq1[8];
    {
        const bf16_t* q0 = qb + (size_t)(row0 + l16) * C_ + quad * 8;
        const bf16_t* q1 = q0 + 16 * C_;
#pragma unroll
        for (int t = 0; t < 8; t++) {
            aq0[t] = *(const bf16x8*)(q0 + t * 32);
            aq1[t] = *(const bf16x8*)(q1 + t * 32);
        }
    }

    f32x4 O0[16], O1[16];
#pragma unroll
    for (int i = 0; i < 16; i++) {
        O0[i] = (f32x4){0.f, 0.f, 0.f, 0.f};
        O1[i] = (f32x4){0.f, 0.f, 0.f, 0.f};
    }
    float lsum0[4] = {0.f, 0.f, 0.f, 0.f};
    float lsum1[4] = {0.f, 0.f, 0.f, 0.f};

    const int s31 = lane & 31, half = lane >> 5;
    const int s3  = lane & 3,  q4   = lane >> 2;

#define STAGE(bufi, j0g)                                                          \
    {                                                                             \
        _Pragma("unroll")                                                         \
        for (int p = 0; p < 4; p++) {                                             \
            int inst = wv * 4 + p;                                                \
            int jl = inst * 2 + half;                                             \
            g2l16(kb + (size_t)((j0g) + jl) * C_ + ((s31 ^ (jl & 7)) << 3),       \
                  &Kbuf[bufi][inst * 512]);                                       \
        }                                                                         \
        _Pragma("unroll")                                                         \
        for (int p = 0; p < 4; p++) {                                             \
            int inst = wv * 4 + p;                                                \
            int cl = inst * 16 + q4;                                              \
            g2l16(vb + (size_t)cl * HW_ + (j0g) + ((s3 ^ (cl & 3)) << 3),         \
                  &Vbuf[bufi][inst * 512]);                                       \
        }                                                                         \
    }

    STAGE(0, jbase)

    bf16_t* pw = &Pt[wv][0];

    for (int tt = 0; tt < tilesPerSplit; tt++) {
        __syncthreads();   // staging for buf[tt&1] done; prev reads done
        if (tt + 1 < tilesPerSplit) STAGE((tt + 1) & 1, jbase + (tt + 1) * 32)

        const bf16_t* Kb = Kbuf[tt & 1];
        const bf16_t* Vb = Vbuf[tt & 1];

        // ---- QK^T: 2 m-tiles x 2 j-subtiles, K-frags reused across m ----
        f32x4 s00 = (f32x4){0.f,0.f,0.f,0.f}, s01 = (f32x4){0.f,0.f,0.f,0.f};
        f32x4 s10 = (f32x4){0.f,0.f,0.f,0.f}, s11 = (f32x4){0.f,0.f,0.f,0.f};
        const int kx = l16 & 7;
#pragma unroll
        for (int t = 0; t < 8; t++) {
            int slot = ((quad + t * 4) ^ kx) << 3;
            bf16x8 bk0 = *(const bf16x8*)(Kb + l16 * 256 + slot);
            bf16x8 bk1 = *(const bf16x8*)(Kb + (16 + l16) * 256 + slot);
            s00 = __builtin_amdgcn_mfma_f32_16x16x32_bf16(aq0[t], bk0, s00, 0, 0, 0);
            s01 = __builtin_amdgcn_mfma_f32_16x16x32_bf16(aq0[t], bk1, s01, 0, 0, 0);
            s10 = __builtin_amdgcn_mfma_f32_16x16x32_bf16(aq1[t], bk0, s10, 0, 0, 0);
            s11 = __builtin_amdgcn_mfma_f32_16x16x32_bf16(aq1[t], bk1, s11, 0, 0, 0);
        }
        // ---- exp, per-lane lsum, P -> LDS ----
#pragma unroll
        for (int r = 0; r < 4; r++) {
            float p00 = __expf(s00[r] * 0.0625f), p01 = __expf(s01[r] * 0.0625f);
            float p10 = __expf(s10[r] * 0.0625f), p11 = __expf(s11[r] * 0.0625f);
            lsum0[r] += p00 + p01;
            lsum1[r] += p10 + p11;
            int ro = (quad * 4 + r) * 40 + l16;
            pw[ro]            = (__bf16)p00;
            pw[ro + 16]       = (__bf16)p01;
            pw[640 + ro]      = (__bf16)p10;
            pw[640 + ro + 16] = (__bf16)p11;
        }
        bf16x8 ap0 = *(const bf16x8*)(pw + l16 * 40 + quad * 8);
        bf16x8 ap1 = *(const bf16x8*)(pw + 640 + l16 * 40 + quad * 8);
        // ---- P.V: V-frags reused across m ----
#pragma unroll
        for (int ct = 0; ct < 16; ct++) {
            int c = ct * 16 + l16;
            bf16x8 bv = *(const bf16x8*)(Vb + c * 32 + ((quad ^ (c & 3)) << 3));
            O0[ct] = __builtin_amdgcn_mfma_f32_16x16x32_bf16(ap0, bv, O0[ct], 0, 0, 0);
            O1[ct] = __builtin_amdgcn_mfma_f32_16x16x32_bf16(ap1, bv, O1[ct], 0, 0, 0);
        }
    }

    // ---- one-time lsum reduction across the 16-lane col groups ----
#pragma unroll
    for (int r = 0; r < 4; r++) {
        float t0 = lsum0[r], t1 = lsum1[r];
        t0 += __shfl_xor(t0, 1); t0 += __shfl_xor(t0, 2);
        t0 += __shfl_xor(t0, 4); t0 += __shfl_xor(t0, 8);
        t1 += __shfl_xor(t1, 1); t1 += __shfl_xor(t1, 2);
        t1 += __shfl_xor(t1, 4); t1 += __shfl_xor(t1, 8);
        lsum0[r] = t0; lsum1[r] = t1;
    }
    float* lp = lpart + (size_t)(js * B_ + b) * HW_;
    if (l16 == 0) {
        float4 a0; a0.x = lsum0[0]; a0.y = lsum0[1]; a0.z = lsum0[2]; a0.w = lsum0[3];
        float4 a1; a1.x = lsum1[0]; a1.y = lsum1[1]; a1.z = lsum1[2]; a1.w = lsum1[3];
        *(float4*)(lp + row0 + quad * 4)      = a0;
        *(float4*)(lp + row0 + 16 + quad * 4) = a1;
    }
    bf16_t* op = Opart + (size_t)(js * B_ + b) * C_ * HW_;
#pragma unroll
    for (int ct = 0; ct < 16; ct++) {
        int c = ct * 16 + l16;
        bf16x4_t v0, v1;
        v0[0] = (__bf16)O0[ct][0]; v0[1] = (__bf16)O0[ct][1];
        v0[2] = (__bf16)O0[ct][2]; v0[3] = (__bf16)O0[ct][3];
        v1[0] = (__bf16)O1[ct][0]; v1[1] = (__bf16)O1[ct][1];
        v1[2] = (__bf16)O1[ct][2]; v1[3] = (__bf16)O1[ct][3];
        *(bf16x4_t*)(op + (size_t)c * HW_ + row0 + quad * 4)      = v0;
        *(bf16x4_t*)(op + (size_t)c * HW_ + row0 + 16 + quad * 4) = v1;
    }
#undef STAGE
}

// ---------------------------------------------------------------------------
__global__ __launch_bounds__(256)
void lsum_combine_kernel(const float* __restrict__ lpart, float* __restrict__ linv, int JS)
{
    int i = blockIdx.x * 256 + threadIdx.x;
    float s = 0.f;
    for (int js = 0; js < JS; js++) s += lpart[(size_t)js * B_ * HW_ + i];
    linv[i] = 1.0f / s;
}

__global__ __launch_bounds__(256)
void epilogue_kernel(const float* __restrict__ x, const bf16_t* __restrict__ Opart,
                     const float* __restrict__ linv, const float* __restrict__ alphaPtr,
                     float* __restrict__ out, int JS)
{
    const float a = *alphaPtr;
    const size_t S = (size_t)B_ * C_ * HW_;
    size_t flat = ((size_t)blockIdx.x * 256 + threadIdx.x) * 4;
    int bc = (int)(flat / HW_);
    int n  = (int)(flat % HW_);
    int b  = bc >> 8;
    float4 xv = *(const float4*)(x + flat);
    float s0 = 0.f, s1 = 0.f, s2 = 0.f, s3 = 0.f;
    for (int js = 0; js < JS; js++) {
        bf16x4_t ov = *(const bf16x4_t*)(Opart + (size_t)js * S + flat);
        s0 += (float)ov[0]; s1 += (float)ov[1];
        s2 += (float)ov[2]; s3 += (float)ov[3];
    }
    float4 lv = *(const float4*)(linv + (size_t)b * HW_ + n);
    float4 r;
    r.x = xv.x + a * s0 * lv.x;
    r.y = xv.y + a * s1 * lv.y;
    r.z = xv.z + a * s2 * lv.z;
    r.w = xv.w + a * s3 * lv.w;
    *(float4*)(out + flat) = r;
}

// ---------------------------------------------------------------------------
extern "C" void kernel_launch(void* const* d_in, const int* in_sizes, int n_in,
                              void* d_out, int out_size, void* d_ws, size_t ws_size,
                              hipStream_t stream)
{
    (void)in_sizes; (void)n_in; (void)out_size;
    const float* x     = (const float*)d_in[0];
    const float* token = (const float*)d_in[1];
    const float* Wq    = (const float*)d_in[2];
    const float* Wk    = (const float*)d_in[3];
    const float* Wv    = (const float*)d_in[4];
    const float* alpha = (const float*)d_in[5];
    float* out = (float*)d_out;

    const size_t S = (size_t)B_ * HW_ * C_;

    int JS = 4;
    for (;;) {
        size_t need = (12 + 2 * (size_t)JS) * S
                    + (size_t)JS * B_ * HW_ * 4 + (size_t)B_ * HW_ * 4;
        if (need <= ws_size || JS == 1) break;
        JS >>= 1;
    }
    const int tilesPerSplit = (HW_ / 32) / JS;

    char* ws = (char*)d_ws;
    bf16_t* qb    = (bf16_t*)(ws);
    bf16_t* kb    = (bf16_t*)(ws + 2 * S);
    bf16_t* vb    = (bf16_t*)(ws + 4 * S);
    bf16_t* xT    = (bf16_t*)(ws + 6 * S);
    bf16_t* tT    = (bf16_t*)(ws + 8 * S);
    bf16_t* Opart = (bf16_t*)(ws + 12 * S);
    float*  lpart = (float*)(ws + (12 + 2 * (size_t)JS) * S);
    float*  linv  = lpart + (size_t)JS * B_ * HW_;

    dim3 blk(256);
    transpose_cast_kernel<C_ ><<<dim3(HW_ / 64, C_  / 64, B_), blk, 0, stream>>>(x,     xT);
    transpose_cast_kernel<TC_><<<dim3(HW_ / 64, TC_ / 64, B_), blk, 0, stream>>>(token, tT);
    convT_kernel<C_ ><<<dim3(HW_ / 64, C_ / 64, B_), blk, 0, stream>>>(xT, Wq, qb);
    convT_kernel<TC_><<<dim3(HW_ / 64, C_ / 64, B_), blk, 0, stream>>>(tT, Wk, kb);
    convV_kernel<TC_><<<dim3(HW_ / 64, C_ / 64, B_), blk, 0, stream>>>(tT, Wv, vb);
    norm_kernel<<<dim3(B_ * HW_ / 4), blk, 0, stream>>>(qb);
    norm_kernel<<<dim3(B_ * HW_ / 4), blk, 0, stream>>>(kb);
    attn_part_kernel<<<dim3(HW_ / 128, JS, B_), blk, 0, stream>>>(qb, kb, vb, Opart, lpart, tilesPerSplit);
    lsum_combine_kernel<<<dim3(B_ * HW_ / 256), blk, 0, stream>>>(lpart, linv, JS);
    epilogue_kernel<<<dim3((int)(S / 1024)), blk, 0, stream>>>(x, Opart, linv, alpha, out, JS);
}

// Round 4
// 349.413 us; speedup vs baseline: 2.2453x; 1.1233x over previous
//
#include <hip/hip_runtime.h>

#define B_   8
#define C_   256
#define TC_  512
#define HW_  2304   // 48*48
#define EPS_ 1e-6f

typedef __bf16 bf16_t;
typedef __bf16 bf16x8 __attribute__((ext_vector_type(8)));
typedef __bf16 bf16x4_t __attribute__((ext_vector_type(4)));
typedef float  f32x4 __attribute__((ext_vector_type(4)));

// async 16B global->LDS; lds base must be wave-uniform (lane i lands at base+16i)
__device__ __forceinline__ void g2l16(const bf16_t* g, bf16_t* l) {
    __builtin_amdgcn_global_load_lds(
        (const __attribute__((address_space(1))) unsigned int*)g,
        (__attribute__((address_space(3))) unsigned int*)l, 16, 0, 0);
}

// ---------------------------------------------------------------------------
// Cast Wq|Wk|Wv fp32 -> bf16.  Region sizes are multiples of 4 floats.
// ---------------------------------------------------------------------------
__global__ __launch_bounds__(256)
void wcast_kernel(const float* __restrict__ wq, const float* __restrict__ wk,
                  const float* __restrict__ wv,
                  bf16_t* __restrict__ oq, bf16_t* __restrict__ ok,
                  bf16_t* __restrict__ ov)
{
    int i4 = (blockIdx.x * 256 + threadIdx.x) * 4;   // 0 .. 327676
    const float* src; bf16_t* dst; int off;
    if (i4 < 65536)       { src = wq; dst = oq; off = i4; }
    else if (i4 < 196608) { src = wk; dst = ok; off = i4 - 65536; }
    else                  { src = wv; dst = ov; off = i4 - 196608; }
    float4 v = *(const float4*)(src + off);
    bf16x4_t o;
    o[0] = (__bf16)v.x; o[1] = (__bf16)v.y; o[2] = (__bf16)v.z; o[3] = (__bf16)v.w;
    *(bf16x4_t*)(dst + off) = o;
}

// ---------------------------------------------------------------------------
// Fused 1x1-conv stage.  Block = 128 thr (2 waves), 32-pixel tile, all 256 o.
//  1. stage X [CIN][HW] fp32 -> LDS T[32 px][CIN] bf16 (transposed)
//  2. wave holds its 16 px rows in regs (af[]): A-frag of the K-GEMM AND
//     B-frag of the V-GEMM (identical lane mapping).
//  3. outA[b][n][o] = normalize_o( sum_c Wa[o][c] X[c][n] )    (q / k)
//  4. if DO_V: outV[b][o][n] = sum_c Wv[o][c] X[c][n]          (v)
// W streamed from L2 as bf16.
// ---------------------------------------------------------------------------
template<int CIN, bool DO_V>
__global__ __launch_bounds__(128, 2)
void convqkv_kernel(const float* __restrict__ X, const bf16_t* __restrict__ Wa,
                    const bf16_t* __restrict__ Wvp, bf16_t* __restrict__ outA,
                    bf16_t* __restrict__ outV)
{
    const int n0 = blockIdx.x * 32;
    const int b  = blockIdx.y;
    const int tid = threadIdx.x;
    const int wv = tid >> 6;
    const int lane = tid & 63;
    const int quad = lane >> 4, l16 = lane & 15;

    __shared__ bf16_t T[32][CIN + 8];

    // ---- stage: fp32 [c][n] -> bf16 T[n][c] ----
    {
        const float* Xb = X + (size_t)b * CIN * HW_ + n0;
        const int cl = tid >> 3;          // 0..15
        const int n4 = (tid & 7) * 4;     // 0..28
        for (int cp = 0; cp < CIN; cp += 16) {
            float4 v = *(const float4*)(Xb + (size_t)(cp + cl) * HW_ + n4);
            T[n4 + 0][cp + cl] = (__bf16)v.x;
            T[n4 + 1][cp + cl] = (__bf16)v.y;
            T[n4 + 2][cp + cl] = (__bf16)v.z;
            T[n4 + 3][cp + cl] = (__bf16)v.w;
        }
    }
    __syncthreads();

    // ---- wave's 16 px rows into registers ----
    bf16x8 af[CIN / 32];
#pragma unroll
    for (int ks = 0; ks < CIN / 32; ks++)
        af[ks] = *(const bf16x8*)(&T[wv * 16 + l16][ks * 32 + quad * 8]);

    f32x4 acc[16];
#pragma unroll
    for (int i = 0; i < 16; i++) acc[i] = (f32x4){0.f, 0.f, 0.f, 0.f};

    // ---- K-GEMM: out[px][o], A=af (px rows), B=Wa rows ----
#pragma unroll
    for (int ot = 0; ot < 16; ot++) {
        const bf16_t* wrow = Wa + (size_t)(ot * 16 + l16) * CIN + quad * 8;
#pragma unroll
        for (int ks = 0; ks < CIN / 32; ks++) {
            bf16x8 bw = *(const bf16x8*)(wrow + ks * 32);
            acc[ot] = __builtin_amdgcn_mfma_f32_16x16x32_bf16(af[ks], bw, acc[ot], 0, 0, 0);
        }
    }

    // ---- fused L2-norm over o (wave owns all 256 o of its px rows) ----
    float scale[4];
#pragma unroll
    for (int r = 0; r < 4; r++) {
        float ss = 0.f;
#pragma unroll
        for (int ot = 0; ot < 16; ot++) ss += acc[ot][r] * acc[ot][r];
        ss += __shfl_xor(ss, 1);
        ss += __shfl_xor(ss, 2);
        ss += __shfl_xor(ss, 4);
        ss += __shfl_xor(ss, 8);
        scale[r] = 1.0f / fmaxf(sqrtf(ss), EPS_);
    }
    // D: row = px-sub = quad*4+r, col = o = ot*16+l16
    {
        bf16_t* oa = outA + ((size_t)b * HW_ + n0 + wv * 16 + quad * 4) * C_ + l16;
#pragma unroll
        for (int ot = 0; ot < 16; ot++)
#pragma unroll
            for (int r = 0; r < 4; r++)
                oa[(size_t)r * C_ + ot * 16] = (__bf16)(acc[ot][r] * scale[r]);
    }

    if (DO_V) {
        // ---- V-GEMM: out[o][px], A=Wv rows, B=af (px cols) ----
#pragma unroll
        for (int i = 0; i < 16; i++) acc[i] = (f32x4){0.f, 0.f, 0.f, 0.f};
#pragma unroll
        for (int ot = 0; ot < 16; ot++) {
            const bf16_t* wrow = Wvp + (size_t)(ot * 16 + l16) * CIN + quad * 8;
#pragma unroll
            for (int ks = 0; ks < CIN / 32; ks++) {
                bf16x8 aw = *(const bf16x8*)(wrow + ks * 32);
                acc[ot] = __builtin_amdgcn_mfma_f32_16x16x32_bf16(aw, af[ks], acc[ot], 0, 0, 0);
            }
        }
        // D: row = o = ot*16+quad*4+r, col = px = n0+wv*16+l16
#pragma unroll
        for (int ot = 0; ot < 16; ot++)
#pragma unroll
            for (int r = 0; r < 4; r++)
                outV[((size_t)b * C_ + ot * 16 + quad * 4 + r) * HW_ + n0 + wv * 16 + l16]
                    = (__bf16)acc[ot][r];
    }
}

// ---------------------------------------------------------------------------
// Attention partials, LDS-staged K/V (double-buffered, swizzled), 2 m-tiles
// per wave (128 Q rows / block).  Unchanged from round 3.
// ---------------------------------------------------------------------------
__global__ __launch_bounds__(256, 2)
void attn_part_kernel(const bf16_t* __restrict__ qn, const bf16_t* __restrict__ kn,
                      const bf16_t* __restrict__ v,
                      bf16_t* __restrict__ Opart, float* __restrict__ lpart,
                      int tilesPerSplit)
{
    const int b    = blockIdx.z;
    const int js   = blockIdx.y;
    const int wv   = threadIdx.x >> 6;
    const int lane = threadIdx.x & 63;
    const int quad = lane >> 4;
    const int l16  = lane & 15;
    const int row0 = blockIdx.x * 128 + wv * 32;
    const int jbase = js * tilesPerSplit * 32;

    const bf16_t* qb = qn + (size_t)b * HW_ * C_;
    const bf16_t* kb = kn + (size_t)b * HW_ * C_;
    const bf16_t* vb = v  + (size_t)b * C_ * HW_;

    __shared__ bf16_t Kbuf[2][32 * 256];
    __shared__ bf16_t Vbuf[2][256 * 32];
    __shared__ bf16_t Pt[4][2 * 16 * 40];

    bf16x8 aq0[8], aq1[8];
    {
        const bf16_t* q0 = qb + (size_t)(row0 + l16) * C_ + quad * 8;
        const bf16_t* q1 = q0 + 16 * C_;
#pragma unroll
        for (int t = 0; t < 8; t++) {
            aq0[t] = *(const bf16x8*)(q0 + t * 32);
            aq1[t] = *(const bf16x8*)(q1 + t * 32);
        }
    }

    f32x4 O0[16], O1[16];
#pragma unroll
    for (int i = 0; i < 16; i++) {
        O0[i] = (f32x4){0.f, 0.f, 0.f, 0.f};
        O1[i] = (f32x4){0.f, 0.f, 0.f, 0.f};
    }
    float lsum0[4] = {0.f, 0.f, 0.f, 0.f};
    float lsum1[4] = {0.f, 0.f, 0.f, 0.f};

    const int s31 = lane & 31, half = lane >> 5;
    const int s3  = lane & 3,  q4   = lane >> 2;

#define STAGE(bufi, j0g)                                                          \
    {                                                                             \
        _Pragma("unroll")                                                         \
        for (int p = 0; p < 4; p++) {                                             \
            int inst = wv * 4 + p;                                                \
            int jl = inst * 2 + half;                                             \
            g2l16(kb + (size_t)((j0g) + jl) * C_ + ((s31 ^ (jl & 7)) << 3),       \
                  &Kbuf[bufi][inst * 512]);                                       \
        }                                                                         \
        _Pragma("unroll")                                                         \
        for (int p = 0; p < 4; p++) {                                             \
            int inst = wv * 4 + p;                                                \
            int cl = inst * 16 + q4;                                              \
            g2l16(vb + (size_t)cl * HW_ + (j0g) + ((s3 ^ (cl & 3)) << 3),         \
                  &Vbuf[bufi][inst * 512]);                                       \
        }                                                                         \
    }

    STAGE(0, jbase)

    bf16_t* pw = &Pt[wv][0];

    for (int tt = 0; tt < tilesPerSplit; tt++) {
        __syncthreads();
        if (tt + 1 < tilesPerSplit) STAGE((tt + 1) & 1, jbase + (tt + 1) * 32)

        const bf16_t* Kb = Kbuf[tt & 1];
        const bf16_t* Vb = Vbuf[tt & 1];

        f32x4 s00 = (f32x4){0.f,0.f,0.f,0.f}, s01 = (f32x4){0.f,0.f,0.f,0.f};
        f32x4 s10 = (f32x4){0.f,0.f,0.f,0.f}, s11 = (f32x4){0.f,0.f,0.f,0.f};
        const int kx = l16 & 7;
#pragma unroll
        for (int t = 0; t < 8; t++) {
            int slot = ((quad + t * 4) ^ kx) << 3;
            bf16x8 bk0 = *(const bf16x8*)(Kb + l16 * 256 + slot);
            bf16x8 bk1 = *(const bf16x8*)(Kb + (16 + l16) * 256 + slot);
            s00 = __builtin_amdgcn_mfma_f32_16x16x32_bf16(aq0[t], bk0, s00, 0, 0, 0);
            s01 = __builtin_amdgcn_mfma_f32_16x16x32_bf16(aq0[t], bk1, s01, 0, 0, 0);
            s10 = __builtin_amdgcn_mfma_f32_16x16x32_bf16(aq1[t], bk0, s10, 0, 0, 0);
            s11 = __builtin_amdgcn_mfma_f32_16x16x32_bf16(aq1[t], bk1, s11, 0, 0, 0);
        }
#pragma unroll
        for (int r = 0; r < 4; r++) {
            float p00 = __expf(s00[r] * 0.0625f), p01 = __expf(s01[r] * 0.0625f);
            float p10 = __expf(s10[r] * 0.0625f), p11 = __expf(s11[r] * 0.0625f);
            lsum0[r] += p00 + p01;
            lsum1[r] += p10 + p11;
            int ro = (quad * 4 + r) * 40 + l16;
            pw[ro]            = (__bf16)p00;
            pw[ro + 16]       = (__bf16)p01;
            pw[640 + ro]      = (__bf16)p10;
            pw[640 + ro + 16] = (__bf16)p11;
        }
        bf16x8 ap0 = *(const bf16x8*)(pw + l16 * 40 + quad * 8);
        bf16x8 ap1 = *(const bf16x8*)(pw + 640 + l16 * 40 + quad * 8);
#pragma unroll
        for (int ct = 0; ct < 16; ct++) {
            int c = ct * 16 + l16;
            bf16x8 bv = *(const bf16x8*)(Vb + c * 32 + ((quad ^ (c & 3)) << 3));
            O0[ct] = __builtin_amdgcn_mfma_f32_16x16x32_bf16(ap0, bv, O0[ct], 0, 0, 0);
            O1[ct] = __builtin_amdgcn_mfma_f32_16x16x32_bf16(ap1, bv, O1[ct], 0, 0, 0);
        }
    }

#pragma unroll
    for (int r = 0; r < 4; r++) {
        float t0 = lsum0[r], t1 = lsum1[r];
        t0 += __shfl_xor(t0, 1); t0 += __shfl_xor(t0, 2);
        t0 += __shfl_xor(t0, 4); t0 += __shfl_xor(t0, 8);
        t1 += __shfl_xor(t1, 1); t1 += __shfl_xor(t1, 2);
        t1 += __shfl_xor(t1, 4); t1 += __shfl_xor(t1, 8);
        lsum0[r] = t0; lsum1[r] = t1;
    }
    float* lp = lpart + (size_t)(js * B_ + b) * HW_;
    if (l16 == 0) {
        float4 a0; a0.x = lsum0[0]; a0.y = lsum0[1]; a0.z = lsum0[2]; a0.w = lsum0[3];
        float4 a1; a1.x = lsum1[0]; a1.y = lsum1[1]; a1.z = lsum1[2]; a1.w = lsum1[3];
        *(float4*)(lp + row0 + quad * 4)      = a0;
        *(float4*)(lp + row0 + 16 + quad * 4) = a1;
    }
    bf16_t* op = Opart + (size_t)(js * B_ + b) * C_ * HW_;
#pragma unroll
    for (int ct = 0; ct < 16; ct++) {
        int c = ct * 16 + l16;
        bf16x4_t v0, v1;
        v0[0] = (__bf16)O0[ct][0]; v0[1] = (__bf16)O0[ct][1];
        v0[2] = (__bf16)O0[ct][2]; v0[3] = (__bf16)O0[ct][3];
        v1[0] = (__bf16)O1[ct][0]; v1[1] = (__bf16)O1[ct][1];
        v1[2] = (__bf16)O1[ct][2]; v1[3] = (__bf16)O1[ct][3];
        *(bf16x4_t*)(op + (size_t)c * HW_ + row0 + quad * 4)      = v0;
        *(bf16x4_t*)(op + (size_t)c * HW_ + row0 + 16 + quad * 4) = v1;
    }
#undef STAGE
}

// ---------------------------------------------------------------------------
// out[b][c][n] = x + alpha * (sum_js Opart) / (sum_js lpart[b][n])
// (lsum combine fused; lpart is L2-hot)
// ---------------------------------------------------------------------------
__global__ __launch_bounds__(256)
void epilogue_kernel(const float* __restrict__ x, const bf16_t* __restrict__ Opart,
                     const float* __restrict__ lpart, const float* __restrict__ alphaPtr,
                     float* __restrict__ out, int JS)
{
    const float a = *alphaPtr;
    const size_t S = (size_t)B_ * C_ * HW_;
    size_t flat = ((size_t)blockIdx.x * 256 + threadIdx.x) * 4;
    int bc = (int)(flat / HW_);
    int n  = (int)(flat % HW_);
    int b  = bc >> 8;
    float4 xv = *(const float4*)(x + flat);
    float s0 = 0.f, s1 = 0.f, s2 = 0.f, s3 = 0.f;
    float l0 = 0.f, l1 = 0.f, l2 = 0.f, l3 = 0.f;
    for (int js = 0; js < JS; js++) {
        bf16x4_t ov = *(const bf16x4_t*)(Opart + (size_t)js * S + flat);
        s0 += (float)ov[0]; s1 += (float)ov[1];
        s2 += (float)ov[2]; s3 += (float)ov[3];
        float4 lv = *(const float4*)(lpart + (size_t)(js * B_ + b) * HW_ + n);
        l0 += lv.x; l1 += lv.y; l2 += lv.z; l3 += lv.w;
    }
    float4 r;
    r.x = xv.x + a * s0 / l0;
    r.y = xv.y + a * s1 / l1;
    r.z = xv.z + a * s2 / l2;
    r.w = xv.w + a * s3 / l3;
    *(float4*)(out + flat) = r;
}

// ---------------------------------------------------------------------------
extern "C" void kernel_launch(void* const* d_in, const int* in_sizes, int n_in,
                              void* d_out, int out_size, void* d_ws, size_t ws_size,
                              hipStream_t stream)
{
    (void)in_sizes; (void)n_in; (void)out_size;
    const float* x     = (const float*)d_in[0];
    const float* token = (const float*)d_in[1];
    const float* Wq    = (const float*)d_in[2];
    const float* Wk    = (const float*)d_in[3];
    const float* Wv    = (const float*)d_in[4];
    const float* alpha = (const float*)d_in[5];
    float* out = (float*)d_out;

    const size_t S = (size_t)B_ * HW_ * C_;   // 4,718,592 elements

    int JS = 4;
    for (;;) {
        size_t need = (12 + 2 * (size_t)JS) * S
                    + (size_t)JS * B_ * HW_ * 4 + (size_t)B_ * HW_ * 4;
        if (need <= ws_size || JS == 1) break;
        JS >>= 1;
    }
    const int tilesPerSplit = (HW_ / 32) / JS;

    char* ws = (char*)d_ws;
    bf16_t* qb    = (bf16_t*)(ws);               // [b][n][C]
    bf16_t* kb    = (bf16_t*)(ws + 2 * S);       // [b][n][C]
    bf16_t* vb    = (bf16_t*)(ws + 4 * S);       // [b][C][n]
    bf16_t* Wqb   = (bf16_t*)(ws + 6 * S);       // 128 KB
    bf16_t* Wkb   = Wqb + (size_t)C_ * C_;       // 256 KB
    bf16_t* Wvb   = Wkb + (size_t)C_ * TC_;      // 256 KB
    bf16_t* Opart = (bf16_t*)(ws + 12 * S);      // [js][b][c][n]
    float*  lpart = (float*)(ws + (12 + 2 * (size_t)JS) * S);

    wcast_kernel<<<dim3(320), dim3(256), 0, stream>>>(Wq, Wk, Wv, Wqb, Wkb, Wvb);
    convqkv_kernel<C_,  false><<<dim3(HW_ / 32, B_), dim3(128), 0, stream>>>(x,     Wqb, nullptr, qb, nullptr);
    convqkv_kernel<TC_, true ><<<dim3(HW_ / 32, B_), dim3(128), 0, stream>>>(token, Wkb, Wvb,     kb, vb);
    attn_part_kernel<<<dim3(HW_ / 128, JS, B_), dim3(256), 0, stream>>>(qb, kb, vb, Opart, lpart, tilesPerSplit);
    epilogue_kernel<<<dim3((int)(S / 1024)), dim3(256), 0, stream>>>(x, Opart, lpart, alpha, out, JS);
}

// Round 5
// 326.312 us; speedup vs baseline: 2.4043x; 1.0708x over previous
//
#include <hip/hip_runtime.h>

#define B_   8
#define C_   256
#define TC_  512
#define HW_  2304   // 48*48
#define EPS_ 1e-6f

typedef __bf16 bf16_t;
typedef __bf16 bf16x8 __attribute__((ext_vector_type(8)));
typedef __bf16 bf16x4_t __attribute__((ext_vector_type(4)));
typedef float  f32x4 __attribute__((ext_vector_type(4)));
typedef unsigned int  u32;
typedef unsigned int  u32x2 __attribute__((ext_vector_type(2)));
typedef unsigned int  u32x4 __attribute__((ext_vector_type(4)));
typedef long long     i64;
typedef unsigned char u8;

// async 16B global->LDS; lds dest is wave-uniform base (lane i -> base+16i);
// global src may be per-lane scattered.
__device__ __forceinline__ void g2l16(const void* g, void* l) {
    __builtin_amdgcn_global_load_lds(
        (const __attribute__((address_space(1))) unsigned int*)g,
        (__attribute__((address_space(3))) unsigned int*)l, 16, 0, 0);
}

// ---------------------------------------------------------------------------
// Cast Wq|Wk|Wv fp32 -> bf16.
// ---------------------------------------------------------------------------
__global__ __launch_bounds__(256)
void wcast_kernel(const float* __restrict__ wq, const float* __restrict__ wk,
                  const float* __restrict__ wv,
                  bf16_t* __restrict__ oq, bf16_t* __restrict__ ok,
                  bf16_t* __restrict__ ov)
{
    int i4 = (blockIdx.x * 256 + threadIdx.x) * 4;
    const float* src; bf16_t* dst; int off;
    if (i4 < 65536)       { src = wq; dst = oq; off = i4; }
    else if (i4 < 196608) { src = wk; dst = ok; off = i4 - 65536; }
    else                  { src = wv; dst = ov; off = i4 - 196608; }
    float4 v = *(const float4*)(src + off);
    bf16x4_t o;
    o[0] = (__bf16)v.x; o[1] = (__bf16)v.y; o[2] = (__bf16)v.z; o[3] = (__bf16)v.w;
    *(bf16x4_t*)(dst + off) = o;
}

// ---------------------------------------------------------------------------
// Fused 1x1-conv stage (unchanged from round 4).
// ---------------------------------------------------------------------------
template<int CIN, bool DO_V>
__global__ __launch_bounds__(128, 2)
void convqkv_kernel(const float* __restrict__ X, const bf16_t* __restrict__ Wa,
                    const bf16_t* __restrict__ Wvp, bf16_t* __restrict__ outA,
                    bf16_t* __restrict__ outV)
{
    const int n0 = blockIdx.x * 32;
    const int b  = blockIdx.y;
    const int tid = threadIdx.x;
    const int wv = tid >> 6;
    const int lane = tid & 63;
    const int quad = lane >> 4, l16 = lane & 15;

    __shared__ bf16_t T[32][CIN + 8];

    {
        const float* Xb = X + (size_t)b * CIN * HW_ + n0;
        const int cl = tid >> 3;
        const int n4 = (tid & 7) * 4;
        for (int cp = 0; cp < CIN; cp += 16) {
            float4 v = *(const float4*)(Xb + (size_t)(cp + cl) * HW_ + n4);
            T[n4 + 0][cp + cl] = (__bf16)v.x;
            T[n4 + 1][cp + cl] = (__bf16)v.y;
            T[n4 + 2][cp + cl] = (__bf16)v.z;
            T[n4 + 3][cp + cl] = (__bf16)v.w;
        }
    }
    __syncthreads();

    bf16x8 af[CIN / 32];
#pragma unroll
    for (int ks = 0; ks < CIN / 32; ks++)
        af[ks] = *(const bf16x8*)(&T[wv * 16 + l16][ks * 32 + quad * 8]);

    f32x4 acc[16];
#pragma unroll
    for (int i = 0; i < 16; i++) acc[i] = (f32x4){0.f, 0.f, 0.f, 0.f};

#pragma unroll
    for (int ot = 0; ot < 16; ot++) {
        const bf16_t* wrow = Wa + (size_t)(ot * 16 + l16) * CIN + quad * 8;
#pragma unroll
        for (int ks = 0; ks < CIN / 32; ks++) {
            bf16x8 bw = *(const bf16x8*)(wrow + ks * 32);
            acc[ot] = __builtin_amdgcn_mfma_f32_16x16x32_bf16(af[ks], bw, acc[ot], 0, 0, 0);
        }
    }

    float scale[4];
#pragma unroll
    for (int r = 0; r < 4; r++) {
        float ss = 0.f;
#pragma unroll
        for (int ot = 0; ot < 16; ot++) ss += acc[ot][r] * acc[ot][r];
        ss += __shfl_xor(ss, 1);
        ss += __shfl_xor(ss, 2);
        ss += __shfl_xor(ss, 4);
        ss += __shfl_xor(ss, 8);
        scale[r] = 1.0f / fmaxf(sqrtf(ss), EPS_);
    }
    {
        bf16_t* oa = outA + ((size_t)b * HW_ + n0 + wv * 16 + quad * 4) * C_ + l16;
#pragma unroll
        for (int ot = 0; ot < 16; ot++)
#pragma unroll
            for (int r = 0; r < 4; r++)
                oa[(size_t)r * C_ + ot * 16] = (__bf16)(acc[ot][r] * scale[r]);
    }

    if (DO_V) {
#pragma unroll
        for (int i = 0; i < 16; i++) acc[i] = (f32x4){0.f, 0.f, 0.f, 0.f};
#pragma unroll
        for (int ot = 0; ot < 16; ot++) {
            const bf16_t* wrow = Wvp + (size_t)(ot * 16 + l16) * CIN + quad * 8;
#pragma unroll
            for (int ks = 0; ks < CIN / 32; ks++) {
                bf16x8 aw = *(const bf16x8*)(wrow + ks * 32);
                acc[ot] = __builtin_amdgcn_mfma_f32_16x16x32_bf16(aw, af[ks], acc[ot], 0, 0, 0);
            }
        }
#pragma unroll
        for (int ot = 0; ot < 16; ot++)
#pragma unroll
            for (int r = 0; r < 4; r++)
                outV[((size_t)b * C_ + ot * 16 + quad * 4 + r) * HW_ + n0 + wv * 16 + l16]
                    = (__bf16)acc[ot][r];
    }
}

// ---------------------------------------------------------------------------
// Flat bf16 -> fp8 e4m3 repack of q|k|v (contiguous 3S elements).
// ---------------------------------------------------------------------------
__global__ __launch_bounds__(256)
void repack8_kernel(const bf16_t* __restrict__ in, u8* __restrict__ out)
{
    size_t i = ((size_t)blockIdx.x * 256 + threadIdx.x) * 8;
    bf16x8 v = *(const bf16x8*)(in + i);
    u32 d0 = __builtin_amdgcn_cvt_pk_fp8_f32((float)v[0], (float)v[1], 0, false);
    d0     = __builtin_amdgcn_cvt_pk_fp8_f32((float)v[2], (float)v[3], d0, true);
    u32 d1 = __builtin_amdgcn_cvt_pk_fp8_f32((float)v[4], (float)v[5], 0, false);
    d1     = __builtin_amdgcn_cvt_pk_fp8_f32((float)v[6], (float)v[7], d1, true);
    u32x2 o; o[0] = d0; o[1] = d1;
    *(u32x2*)(out + i) = o;
}

// ---------------------------------------------------------------------------
// Attention partials, fp8 operands / fp32 accum.
// q8,k8: fp8 [b][n][C] ; v8: fp8 [b][c][n].
// K LDS: chunk-major [s 0..15][j 0..31] 16B granules (addr s*512+j*16).
// V LDS: row-major   [c 0..255][32 B]   (addr c*32).
// P LDS: per-wave [m 16][48 B], cols interleaved (col c -> byte 2c, col c+16
//        -> byte 2c+1), written via cvt_pk_fp8 pairs, read b128 + v_perm.
// ---------------------------------------------------------------------------
__global__ __launch_bounds__(256, 2)
void attn_part_kernel(const u8* __restrict__ q8, const u8* __restrict__ k8,
                      const u8* __restrict__ v8,
                      bf16_t* __restrict__ Opart, float* __restrict__ lpart,
                      int tilesPerSplit)
{
    const int b    = blockIdx.z;
    const int js   = blockIdx.y;
    const int wv   = threadIdx.x >> 6;
    const int lane = threadIdx.x & 63;
    const int quad = lane >> 4;
    const int l16  = lane & 15;
    const int row0 = blockIdx.x * 128 + wv * 32;
    const int jbase = js * tilesPerSplit * 32;

    const u8* qb = q8 + (size_t)b * HW_ * C_;
    const u8* kb = k8 + (size_t)b * HW_ * C_;
    const u8* vb = v8 + (size_t)b * C_ * HW_;

    __shared__ u8 Kbuf[2][8192];
    __shared__ u8 Vbuf[2][8192];
    __shared__ u8 Pt[4][1536];

    // Q fragments: A[m=l16][k=t*32+quad*8+i], 8 fp8 = i64 per frag
    i64 aq0[8], aq1[8];
    {
        const u8* r0 = qb + (size_t)(row0 + l16) * C_ + quad * 8;
        const u8* r1 = r0 + 16 * C_;
#pragma unroll
        for (int t = 0; t < 8; t++) {
            aq0[t] = *(const i64*)(r0 + t * 32);
            aq1[t] = *(const i64*)(r1 + t * 32);
        }
    }

    f32x4 O0[16], O1[16];
#pragma unroll
    for (int i = 0; i < 16; i++) {
        O0[i] = (f32x4){0.f, 0.f, 0.f, 0.f};
        O1[i] = (f32x4){0.f, 0.f, 0.f, 0.f};
    }
    float lsum0[4] = {0.f, 0.f, 0.f, 0.f};
    float lsum1[4] = {0.f, 0.f, 0.f, 0.f};

    // staging lane mappings
    const int kj = lane & 31;          // K: row j-local
    const int kh = lane >> 5;          // K: chunk parity
    const int vg = lane & 1;           // V: granule
    const int vc = lane >> 1;          // V: row c-local (i*32 + vc)

#define STAGE(bufi, j0g)                                                       \
    {                                                                          \
        _Pragma("unroll")                                                      \
        for (int p = 0; p < 2; p++) {                                          \
            int i = wv * 2 + p;                                                \
            int s = i * 2 + kh;                                                \
            g2l16(kb + (size_t)((j0g) + kj) * C_ + s * 16,                     \
                  &Kbuf[bufi][i * 1024]);                                      \
        }                                                                      \
        _Pragma("unroll")                                                      \
        for (int p = 0; p < 2; p++) {                                          \
            int i = wv * 2 + p;                                                \
            int c = i * 32 + vc;                                               \
            g2l16(vb + (size_t)c * HW_ + (j0g) + vg * 16,                      \
                  &Vbuf[bufi][i * 1024]);                                      \
        }                                                                      \
    }

    STAGE(0, jbase)

    u8* pw = &Pt[wv][0];
    const int koff = (quad >> 1) * 512 + l16 * 16 + (quad & 1) * 8;
    const u32 sel = (quad < 2) ? 0x06040200u : 0x07050301u;

    for (int tt = 0; tt < tilesPerSplit; tt++) {
        __syncthreads();   // staging for buf[tt&1] done; prev reads done
        if (tt + 1 < tilesPerSplit) STAGE((tt + 1) & 1, jbase + (tt + 1) * 32)

        const u8* Kb = Kbuf[tt & 1];
        const u8* Vb = Vbuf[tt & 1];

        // ---- QK^T ----
        f32x4 s00 = (f32x4){0.f,0.f,0.f,0.f}, s01 = (f32x4){0.f,0.f,0.f,0.f};
        f32x4 s10 = (f32x4){0.f,0.f,0.f,0.f}, s11 = (f32x4){0.f,0.f,0.f,0.f};
#pragma unroll
        for (int t = 0; t < 8; t++) {
            i64 bk0 = *(const i64*)(Kb + t * 1024 + koff);
            i64 bk1 = *(const i64*)(Kb + t * 1024 + koff + 256);
            s00 = __builtin_amdgcn_mfma_f32_16x16x32_fp8_fp8(aq0[t], bk0, s00, 0, 0, 0);
            s01 = __builtin_amdgcn_mfma_f32_16x16x32_fp8_fp8(aq0[t], bk1, s01, 0, 0, 0);
            s10 = __builtin_amdgcn_mfma_f32_16x16x32_fp8_fp8(aq1[t], bk0, s10, 0, 0, 0);
            s11 = __builtin_amdgcn_mfma_f32_16x16x32_fp8_fp8(aq1[t], bk1, s11, 0, 0, 0);
        }
        // ---- exp, per-lane lsum, P (fp8 interleaved) -> LDS ----
#pragma unroll
        for (int r = 0; r < 4; r++) {
            float p00 = __expf(s00[r] * 0.0625f), p01 = __expf(s01[r] * 0.0625f);
            float p10 = __expf(s10[r] * 0.0625f), p11 = __expf(s11[r] * 0.0625f);
            lsum0[r] += p00 + p01;
            lsum1[r] += p10 + p11;
            u32 w0 = __builtin_amdgcn_cvt_pk_fp8_f32(p00, p01, 0, false);
            u32 w1 = __builtin_amdgcn_cvt_pk_fp8_f32(p10, p11, 0, false);
            int ro = (quad * 4 + r) * 48 + l16 * 2;
            *(short*)(pw + ro)       = (short)w0;
            *(short*)(pw + 768 + ro) = (short)w1;
        }
        // ---- P read-back as fp8 A-frags (deinterleave via v_perm) ----
        i64 ap0, ap1;
        {
            u32x4 d = *(const u32x4*)(pw + l16 * 48 + (quad & 1) * 16);
            u32 lo = __builtin_amdgcn_perm(d[1], d[0], sel);
            u32 hi = __builtin_amdgcn_perm(d[3], d[2], sel);
            ap0 = ((i64)hi << 32) | (i64)lo;
            u32x4 e = *(const u32x4*)(pw + 768 + l16 * 48 + (quad & 1) * 16);
            lo = __builtin_amdgcn_perm(e[1], e[0], sel);
            hi = __builtin_amdgcn_perm(e[3], e[2], sel);
            ap1 = ((i64)hi << 32) | (i64)lo;
        }
        // ---- P.V ----
#pragma unroll
        for (int ct = 0; ct < 16; ct++) {
            i64 bv = *(const i64*)(Vb + ct * 512 + l16 * 32 + quad * 8);
            O0[ct] = __builtin_amdgcn_mfma_f32_16x16x32_fp8_fp8(ap0, bv, O0[ct], 0, 0, 0);
            O1[ct] = __builtin_amdgcn_mfma_f32_16x16x32_fp8_fp8(ap1, bv, O1[ct], 0, 0, 0);
        }
    }

    // ---- one-time lsum reduction ----
#pragma unroll
    for (int r = 0; r < 4; r++) {
        float t0 = lsum0[r], t1 = lsum1[r];
        t0 += __shfl_xor(t0, 1); t0 += __shfl_xor(t0, 2);
        t0 += __shfl_xor(t0, 4); t0 += __shfl_xor(t0, 8);
        t1 += __shfl_xor(t1, 1); t1 += __shfl_xor(t1, 2);
        t1 += __shfl_xor(t1, 4); t1 += __shfl_xor(t1, 8);
        lsum0[r] = t0; lsum1[r] = t1;
    }
    float* lp = lpart + (size_t)(js * B_ + b) * HW_;
    if (l16 == 0) {
        float4 a0; a0.x = lsum0[0]; a0.y = lsum0[1]; a0.z = lsum0[2]; a0.w = lsum0[3];
        float4 a1; a1.x = lsum1[0]; a1.y = lsum1[1]; a1.z = lsum1[2]; a1.w = lsum1[3];
        *(float4*)(lp + row0 + quad * 4)      = a0;
        *(float4*)(lp + row0 + 16 + quad * 4) = a1;
    }
    bf16_t* op = Opart + (size_t)(js * B_ + b) * C_ * HW_;
#pragma unroll
    for (int ct = 0; ct < 16; ct++) {
        int c = ct * 16 + l16;
        bf16x4_t v0, v1;
        v0[0] = (__bf16)O0[ct][0]; v0[1] = (__bf16)O0[ct][1];
        v0[2] = (__bf16)O0[ct][2]; v0[3] = (__bf16)O0[ct][3];
        v1[0] = (__bf16)O1[ct][0]; v1[1] = (__bf16)O1[ct][1];
        v1[2] = (__bf16)O1[ct][2]; v1[3] = (__bf16)O1[ct][3];
        *(bf16x4_t*)(op + (size_t)c * HW_ + row0 + quad * 4)      = v0;
        *(bf16x4_t*)(op + (size_t)c * HW_ + row0 + 16 + quad * 4) = v1;
    }
#undef STAGE
}

// ---------------------------------------------------------------------------
// out[b][c][n] = x + alpha * (sum_js Opart) / (sum_js lpart[b][n])
// ---------------------------------------------------------------------------
__global__ __launch_bounds__(256)
void epilogue_kernel(const float* __restrict__ x, const bf16_t* __restrict__ Opart,
                     const float* __restrict__ lpart, const float* __restrict__ alphaPtr,
                     float* __restrict__ out, int JS)
{
    const float a = *alphaPtr;
    const size_t S = (size_t)B_ * C_ * HW_;
    size_t flat = ((size_t)blockIdx.x * 256 + threadIdx.x) * 4;
    int bc = (int)(flat / HW_);
    int n  = (int)(flat % HW_);
    int b  = bc >> 8;
    float4 xv = *(const float4*)(x + flat);
    float s0 = 0.f, s1 = 0.f, s2 = 0.f, s3 = 0.f;
    float l0 = 0.f, l1 = 0.f, l2 = 0.f, l3 = 0.f;
    for (int js = 0; js < JS; js++) {
        bf16x4_t ov = *(const bf16x4_t*)(Opart + (size_t)js * S + flat);
        s0 += (float)ov[0]; s1 += (float)ov[1];
        s2 += (float)ov[2]; s3 += (float)ov[3];
        float4 lv = *(const float4*)(lpart + (size_t)(js * B_ + b) * HW_ + n);
        l0 += lv.x; l1 += lv.y; l2 += lv.z; l3 += lv.w;
    }
    float4 r;
    r.x = xv.x + a * s0 / l0;
    r.y = xv.y + a * s1 / l1;
    r.z = xv.z + a * s2 / l2;
    r.w = xv.w + a * s3 / l3;
    *(float4*)(out + flat) = r;
}

// ---------------------------------------------------------------------------
extern "C" void kernel_launch(void* const* d_in, const int* in_sizes, int n_in,
                              void* d_out, int out_size, void* d_ws, size_t ws_size,
                              hipStream_t stream)
{
    (void)in_sizes; (void)n_in; (void)out_size;
    const float* x     = (const float*)d_in[0];
    const float* token = (const float*)d_in[1];
    const float* Wq    = (const float*)d_in[2];
    const float* Wk    = (const float*)d_in[3];
    const float* Wv    = (const float*)d_in[4];
    const float* Wvv   = (const float*)d_in[4];
    (void)Wvv;
    const float* alpha = (const float*)d_in[5];
    float* out = (float*)d_out;

    const size_t S = (size_t)B_ * HW_ * C_;   // 4,718,592 elements

    int JS = 4;
    for (;;) {
        size_t need = (12 + 2 * (size_t)JS) * S
                    + (size_t)JS * B_ * HW_ * 4 + (size_t)B_ * HW_ * 4;
        if (need <= ws_size || JS == 1) break;
        JS >>= 1;
    }
    const int tilesPerSplit = (HW_ / 32) / JS;

    char* ws = (char*)d_ws;
    bf16_t* qb    = (bf16_t*)(ws);               // [b][n][C]   bf16 (2S bytes @0)
    bf16_t* kb    = (bf16_t*)(ws + 2 * S);       // [b][n][C]   bf16
    bf16_t* vb    = (bf16_t*)(ws + 4 * S);       // [b][C][n]   bf16
    bf16_t* Wqb   = (bf16_t*)(ws + 6 * S);       // 128 KB
    bf16_t* Wkb   = Wqb + (size_t)C_ * C_;       // 256 KB
    bf16_t* Wvb   = Wkb + (size_t)C_ * TC_;      // 256 KB
    u8*     q8    = (u8*)(ws + 7 * S);           // fp8 [b][n][C]
    u8*     k8    = (u8*)(ws + 8 * S);           // fp8 [b][n][C]
    u8*     v8    = (u8*)(ws + 9 * S);           // fp8 [b][C][n]
    bf16_t* Opart = (bf16_t*)(ws + 12 * S);      // [js][b][c][n] bf16
    float*  lpart = (float*)(ws + (12 + 2 * (size_t)JS) * S);

    wcast_kernel<<<dim3(320), dim3(256), 0, stream>>>(Wq, Wk, Wv, Wqb, Wkb, Wvb);
    convqkv_kernel<C_,  false><<<dim3(HW_ / 32, B_), dim3(128), 0, stream>>>(x,     Wqb, nullptr, qb, nullptr);
    convqkv_kernel<TC_, true ><<<dim3(HW_ / 32, B_), dim3(128), 0, stream>>>(token, Wkb, Wvb,     kb, vb);
    // qb|kb|vb are contiguous 3S bf16 elements at ws+0 -> fp8 at ws+7S
    repack8_kernel<<<dim3(6912), dim3(256), 0, stream>>>((const bf16_t*)ws, q8);
    attn_part_kernel<<<dim3(HW_ / 128, JS, B_), dim3(256), 0, stream>>>(q8, k8, v8, Opart, lpart, tilesPerSplit);
    epilogue_kernel<<<dim3((int)(S / 1024)), dim3(256), 0, stream>>>(x, Opart, lpart, alpha, out, JS);
}

// Round 6
// 310.349 us; speedup vs baseline: 2.5279x; 1.0514x over previous
//
#include <hip/hip_runtime.h>

#define B_   8
#define C_   256
#define TC_  512
#define HW_  2304   // 48*48
#define EPS_ 1e-6f

typedef __bf16 bf16_t;
typedef __bf16 bf16x8 __attribute__((ext_vector_type(8)));
typedef __bf16 bf16x4_t __attribute__((ext_vector_type(4)));
typedef float  f32x4 __attribute__((ext_vector_type(4)));
typedef unsigned int  u32;
typedef unsigned int  u32x2 __attribute__((ext_vector_type(2)));
typedef unsigned int  u32x4 __attribute__((ext_vector_type(4)));
typedef long long     i64;
typedef unsigned char u8;

// async 16B global->LDS; lds dest is wave-uniform base (lane i -> base+16i);
// global src may be per-lane scattered.
__device__ __forceinline__ void g2l16(const void* g, void* l) {
    __builtin_amdgcn_global_load_lds(
        (const __attribute__((address_space(1))) unsigned int*)g,
        (__attribute__((address_space(3))) unsigned int*)l, 16, 0, 0);
}

// ---------------------------------------------------------------------------
// Cast Wq|Wk|Wv fp32 -> bf16.
// ---------------------------------------------------------------------------
__global__ __launch_bounds__(256)
void wcast_kernel(const float* __restrict__ wq, const float* __restrict__ wk,
                  const float* __restrict__ wv,
                  bf16_t* __restrict__ oq, bf16_t* __restrict__ ok,
                  bf16_t* __restrict__ ov)
{
    int i4 = (blockIdx.x * 256 + threadIdx.x) * 4;
    const float* src; bf16_t* dst; int off;
    if (i4 < 65536)       { src = wq; dst = oq; off = i4; }
    else if (i4 < 196608) { src = wk; dst = ok; off = i4 - 65536; }
    else                  { src = wv; dst = ov; off = i4 - 196608; }
    float4 v = *(const float4*)(src + off);
    bf16x4_t o;
    o[0] = (__bf16)v.x; o[1] = (__bf16)v.y; o[2] = (__bf16)v.z; o[3] = (__bf16)v.w;
    *(bf16x4_t*)(dst + off) = o;
}

// ---------------------------------------------------------------------------
// Fused 1x1-conv stage, o-split for occupancy.
// Block = 256 thr (4 waves), 16-pixel tile; wave wv owns o-tiles
// [wv*64, wv*64+63] of BOTH the K-GEMM and (if DO_V) the V-GEMM.
//  1. stage X [CIN][HW] fp32 -> LDS T[16 px][CIN] bf16 (transposed)
//  2. every wave holds all 16 px rows in regs (af[]): A-frag of K-GEMM and
//     B-frag of V-GEMM (identical lane mapping).
//  3. outA[b][n][o] = normalize_o( sum_c Wa[o][c] X[c][n] )   (q / k)
//     (norm over o crosses waves: shfl partial -> ssp[4][16] -> combine)
//  4. if DO_V: outV[b][o][n] = sum_c Wv[o][c] X[c][n]         (v)
// W streamed from L2 as bf16.
// ---------------------------------------------------------------------------
template<int CIN, bool DO_V>
__global__ __launch_bounds__(256, 4)
void convqkv_kernel(const float* __restrict__ X, const bf16_t* __restrict__ Wa,
                    const bf16_t* __restrict__ Wvp, bf16_t* __restrict__ outA,
                    bf16_t* __restrict__ outV)
{
    const int n0 = blockIdx.x * 16;
    const int b  = blockIdx.y;
    const int tid = threadIdx.x;
    const int wv = tid >> 6;
    const int lane = tid & 63;
    const int quad = lane >> 4, l16 = lane & 15;

    __shared__ bf16_t T[16][CIN + 8];
    __shared__ float ssp[4][16];

    // ---- stage: fp32 [c][n] -> bf16 T[n][c] ----
    {
        const float* Xb = X + (size_t)b * CIN * HW_ + n0;
        const int cl = tid >> 2;          // 0..63
        const int n4 = (tid & 3) * 4;     // 0,4,8,12
#pragma unroll
        for (int cp = 0; cp < CIN; cp += 64) {
            float4 v = *(const float4*)(Xb + (size_t)(cp + cl) * HW_ + n4);
            T[n4 + 0][cp + cl] = (__bf16)v.x;
            T[n4 + 1][cp + cl] = (__bf16)v.y;
            T[n4 + 2][cp + cl] = (__bf16)v.z;
            T[n4 + 3][cp + cl] = (__bf16)v.w;
        }
    }
    __syncthreads();

    // ---- all 16 px rows into registers (same in every wave) ----
    bf16x8 af[CIN / 32];
#pragma unroll
    for (int ks = 0; ks < CIN / 32; ks++)
        af[ks] = *(const bf16x8*)(&T[l16][ks * 32 + quad * 8]);

    const int ot0 = wv * 4;

    // ---- K-GEMM: out[px][o], A=af (px rows), B=Wa rows (wave's 4 ot) ----
    f32x4 accK[4];
#pragma unroll
    for (int p = 0; p < 4; p++) accK[p] = (f32x4){0.f, 0.f, 0.f, 0.f};
#pragma unroll
    for (int p = 0; p < 4; p++) {
        const bf16_t* wrow = Wa + (size_t)((ot0 + p) * 16 + l16) * CIN + quad * 8;
#pragma unroll
        for (int ks = 0; ks < CIN / 32; ks++) {
            bf16x8 bw = *(const bf16x8*)(wrow + ks * 32);
            accK[p] = __builtin_amdgcn_mfma_f32_16x16x32_bf16(af[ks], bw, accK[p], 0, 0, 0);
        }
    }

    // ---- per-wave partial sum of squares over this wave's 64 o ----
    {
        float ssr[4];
#pragma unroll
        for (int r = 0; r < 4; r++) {
            float ss = accK[0][r] * accK[0][r] + accK[1][r] * accK[1][r]
                     + accK[2][r] * accK[2][r] + accK[3][r] * accK[3][r];
            ss += __shfl_xor(ss, 1);
            ss += __shfl_xor(ss, 2);
            ss += __shfl_xor(ss, 4);
            ss += __shfl_xor(ss, 8);
            ssr[r] = ss;
        }
        if (l16 == 0) {
#pragma unroll
            for (int r = 0; r < 4; r++) ssp[wv][quad * 4 + r] = ssr[r];
        }
    }

    // ---- V-GEMM (hides the ssp barrier): out[o][px], A=Wv rows, B=af ----
    f32x4 accV[4];
    if (DO_V) {
#pragma unroll
        for (int p = 0; p < 4; p++) accV[p] = (f32x4){0.f, 0.f, 0.f, 0.f};
#pragma unroll
        for (int p = 0; p < 4; p++) {
            const bf16_t* wrow = Wvp + (size_t)((ot0 + p) * 16 + l16) * CIN + quad * 8;
#pragma unroll
            for (int ks = 0; ks < CIN / 32; ks++) {
                bf16x8 aw = *(const bf16x8*)(wrow + ks * 32);
                accV[p] = __builtin_amdgcn_mfma_f32_16x16x32_bf16(aw, af[ks], accV[p], 0, 0, 0);
            }
        }
    }

    __syncthreads();

    // ---- combine norm partials, scale, write K/A out ----
    float scale[4];
#pragma unroll
    for (int r = 0; r < 4; r++) {
        int px = quad * 4 + r;
        float s = ssp[0][px] + ssp[1][px] + ssp[2][px] + ssp[3][px];
        scale[r] = 1.0f / fmaxf(sqrtf(s), EPS_);
    }
    {
        // D: row = px = quad*4+r, col = o = (ot0+p)*16 + l16
        bf16_t* oa = outA + ((size_t)b * HW_ + n0 + quad * 4) * C_ + l16;
#pragma unroll
        for (int p = 0; p < 4; p++)
#pragma unroll
            for (int r = 0; r < 4; r++)
                oa[(size_t)r * C_ + (ot0 + p) * 16] = (__bf16)(accK[p][r] * scale[r]);
    }

    if (DO_V) {
        // D: row = o = (ot0+p)*16 + quad*4 + r, col = px = n0 + l16
#pragma unroll
        for (int p = 0; p < 4; p++)
#pragma unroll
            for (int r = 0; r < 4; r++)
                outV[((size_t)b * C_ + (ot0 + p) * 16 + quad * 4 + r) * HW_ + n0 + l16]
                    = (__bf16)accV[p][r];
    }
}

// ---------------------------------------------------------------------------
// Flat bf16 -> fp8 e4m3 repack of q|k|v (contiguous 3S elements).
// ---------------------------------------------------------------------------
__global__ __launch_bounds__(256)
void repack8_kernel(const bf16_t* __restrict__ in, u8* __restrict__ out)
{
    size_t i = ((size_t)blockIdx.x * 256 + threadIdx.x) * 8;
    bf16x8 v = *(const bf16x8*)(in + i);
    u32 d0 = __builtin_amdgcn_cvt_pk_fp8_f32((float)v[0], (float)v[1], 0, false);
    d0     = __builtin_amdgcn_cvt_pk_fp8_f32((float)v[2], (float)v[3], d0, true);
    u32 d1 = __builtin_amdgcn_cvt_pk_fp8_f32((float)v[4], (float)v[5], 0, false);
    d1     = __builtin_amdgcn_cvt_pk_fp8_f32((float)v[6], (float)v[7], d1, true);
    u32x2 o; o[0] = d0; o[1] = d1;
    *(u32x2*)(out + i) = o;
}

// ---------------------------------------------------------------------------
// Attention partials, fp8 operands / fp32 accum (unchanged from round 5).
// ---------------------------------------------------------------------------
__global__ __launch_bounds__(256, 2)
void attn_part_kernel(const u8* __restrict__ q8, const u8* __restrict__ k8,
                      const u8* __restrict__ v8,
                      bf16_t* __restrict__ Opart, float* __restrict__ lpart,
                      int tilesPerSplit)
{
    const int b    = blockIdx.z;
    const int js   = blockIdx.y;
    const int wv   = threadIdx.x >> 6;
    const int lane = threadIdx.x & 63;
    const int quad = lane >> 4;
    const int l16  = lane & 15;
    const int row0 = blockIdx.x * 128 + wv * 32;
    const int jbase = js * tilesPerSplit * 32;

    const u8* qb = q8 + (size_t)b * HW_ * C_;
    const u8* kb = k8 + (size_t)b * HW_ * C_;
    const u8* vb = v8 + (size_t)b * C_ * HW_;

    __shared__ u8 Kbuf[2][8192];
    __shared__ u8 Vbuf[2][8192];
    __shared__ u8 Pt[4][1536];

    i64 aq0[8], aq1[8];
    {
        const u8* r0 = qb + (size_t)(row0 + l16) * C_ + quad * 8;
        const u8* r1 = r0 + 16 * C_;
#pragma unroll
        for (int t = 0; t < 8; t++) {
            aq0[t] = *(const i64*)(r0 + t * 32);
            aq1[t] = *(const i64*)(r1 + t * 32);
        }
    }

    f32x4 O0[16], O1[16];
#pragma unroll
    for (int i = 0; i < 16; i++) {
        O0[i] = (f32x4){0.f, 0.f, 0.f, 0.f};
        O1[i] = (f32x4){0.f, 0.f, 0.f, 0.f};
    }
    float lsum0[4] = {0.f, 0.f, 0.f, 0.f};
    float lsum1[4] = {0.f, 0.f, 0.f, 0.f};

    const int kj = lane & 31;
    const int kh = lane >> 5;
    const int vg = lane & 1;
    const int vc = lane >> 1;

#define STAGE(bufi, j0g)                                                       \
    {                                                                          \
        _Pragma("unroll")                                                      \
        for (int p = 0; p < 2; p++) {                                          \
            int i = wv * 2 + p;                                                \
            int s = i * 2 + kh;                                                \
            g2l16(kb + (size_t)((j0g) + kj) * C_ + s * 16,                     \
                  &Kbuf[bufi][i * 1024]);                                      \
        }                                                                      \
        _Pragma("unroll")                                                      \
        for (int p = 0; p < 2; p++) {                                          \
            int i = wv * 2 + p;                                                \
            int c = i * 32 + vc;                                               \
            g2l16(vb + (size_t)c * HW_ + (j0g) + vg * 16,                      \
                  &Vbuf[bufi][i * 1024]);                                      \
        }                                                                      \
    }

    STAGE(0, jbase)

    u8* pw = &Pt[wv][0];
    const int koff = (quad >> 1) * 512 + l16 * 16 + (quad & 1) * 8;
    const u32 sel = (quad < 2) ? 0x06040200u : 0x07050301u;

    for (int tt = 0; tt < tilesPerSplit; tt++) {
        __syncthreads();
        if (tt + 1 < tilesPerSplit) STAGE((tt + 1) & 1, jbase + (tt + 1) * 32)

        const u8* Kb = Kbuf[tt & 1];
        const u8* Vb = Vbuf[tt & 1];

        f32x4 s00 = (f32x4){0.f,0.f,0.f,0.f}, s01 = (f32x4){0.f,0.f,0.f,0.f};
        f32x4 s10 = (f32x4){0.f,0.f,0.f,0.f}, s11 = (f32x4){0.f,0.f,0.f,0.f};
#pragma unroll
        for (int t = 0; t < 8; t++) {
            i64 bk0 = *(const i64*)(Kb + t * 1024 + koff);
            i64 bk1 = *(const i64*)(Kb + t * 1024 + koff + 256);
            s00 = __builtin_amdgcn_mfma_f32_16x16x32_fp8_fp8(aq0[t], bk0, s00, 0, 0, 0);
            s01 = __builtin_amdgcn_mfma_f32_16x16x32_fp8_fp8(aq0[t], bk1, s01, 0, 0, 0);
            s10 = __builtin_amdgcn_mfma_f32_16x16x32_fp8_fp8(aq1[t], bk0, s10, 0, 0, 0);
            s11 = __builtin_amdgcn_mfma_f32_16x16x32_fp8_fp8(aq1[t], bk1, s11, 0, 0, 0);
        }
#pragma unroll
        for (int r = 0; r < 4; r++) {
            float p00 = __expf(s00[r] * 0.0625f), p01 = __expf(s01[r] * 0.0625f);
            float p10 = __expf(s10[r] * 0.0625f), p11 = __expf(s11[r] * 0.0625f);
            lsum0[r] += p00 + p01;
            lsum1[r] += p10 + p11;
            u32 w0 = __builtin_amdgcn_cvt_pk_fp8_f32(p00, p01, 0, false);
            u32 w1 = __builtin_amdgcn_cvt_pk_fp8_f32(p10, p11, 0, false);
            int ro = (quad * 4 + r) * 48 + l16 * 2;
            *(short*)(pw + ro)       = (short)w0;
            *(short*)(pw + 768 + ro) = (short)w1;
        }
        i64 ap0, ap1;
        {
            u32x4 d = *(const u32x4*)(pw + l16 * 48 + (quad & 1) * 16);
            u32 lo = __builtin_amdgcn_perm(d[1], d[0], sel);
            u32 hi = __builtin_amdgcn_perm(d[3], d[2], sel);
            ap0 = ((i64)hi << 32) | (i64)lo;
            u32x4 e = *(const u32x4*)(pw + 768 + l16 * 48 + (quad & 1) * 16);
            lo = __builtin_amdgcn_perm(e[1], e[0], sel);
            hi = __builtin_amdgcn_perm(e[3], e[2], sel);
            ap1 = ((i64)hi << 32) | (i64)lo;
        }
#pragma unroll
        for (int ct = 0; ct < 16; ct++) {
            i64 bv = *(const i64*)(Vb + ct * 512 + l16 * 32 + quad * 8);
            O0[ct] = __builtin_amdgcn_mfma_f32_16x16x32_fp8_fp8(ap0, bv, O0[ct], 0, 0, 0);
            O1[ct] = __builtin_amdgcn_mfma_f32_16x16x32_fp8_fp8(ap1, bv, O1[ct], 0, 0, 0);
        }
    }

#pragma unroll
    for (int r = 0; r < 4; r++) {
        float t0 = lsum0[r], t1 = lsum1[r];
        t0 += __shfl_xor(t0, 1); t0 += __shfl_xor(t0, 2);
        t0 += __shfl_xor(t0, 4); t0 += __shfl_xor(t0, 8);
        t1 += __shfl_xor(t1, 1); t1 += __shfl_xor(t1, 2);
        t1 += __shfl_xor(t1, 4); t1 += __shfl_xor(t1, 8);
        lsum0[r] = t0; lsum1[r] = t1;
    }
    float* lp = lpart + (size_t)(js * B_ + b) * HW_;
    if (l16 == 0) {
        float4 a0; a0.x = lsum0[0]; a0.y = lsum0[1]; a0.z = lsum0[2]; a0.w = lsum0[3];
        float4 a1; a1.x = lsum1[0]; a1.y = lsum1[1]; a1.z = lsum1[2]; a1.w = lsum1[3];
        *(float4*)(lp + row0 + quad * 4)      = a0;
        *(float4*)(lp + row0 + 16 + quad * 4) = a1;
    }
    bf16_t* op = Opart + (size_t)(js * B_ + b) * C_ * HW_;
#pragma unroll
    for (int ct = 0; ct < 16; ct++) {
        int c = ct * 16 + l16;
        bf16x4_t v0, v1;
        v0[0] = (__bf16)O0[ct][0]; v0[1] = (__bf16)O0[ct][1];
        v0[2] = (__bf16)O0[ct][2]; v0[3] = (__bf16)O0[ct][3];
        v1[0] = (__bf16)O1[ct][0]; v1[1] = (__bf16)O1[ct][1];
        v1[2] = (__bf16)O1[ct][2]; v1[3] = (__bf16)O1[ct][3];
        *(bf16x4_t*)(op + (size_t)c * HW_ + row0 + quad * 4)      = v0;
        *(bf16x4_t*)(op + (size_t)c * HW_ + row0 + 16 + quad * 4) = v1;
    }
#undef STAGE
}

// ---------------------------------------------------------------------------
// out[b][c][n] = x + alpha * (sum_js Opart) / (sum_js lpart[b][n])
// ---------------------------------------------------------------------------
__global__ __launch_bounds__(256)
void epilogue_kernel(const float* __restrict__ x, const bf16_t* __restrict__ Opart,
                     const float* __restrict__ lpart, const float* __restrict__ alphaPtr,
                     float* __restrict__ out, int JS)
{
    const float a = *alphaPtr;
    const size_t S = (size_t)B_ * C_ * HW_;
    size_t flat = ((size_t)blockIdx.x * 256 + threadIdx.x) * 4;
    int bc = (int)(flat / HW_);
    int n  = (int)(flat % HW_);
    int b  = bc >> 8;
    float4 xv = *(const float4*)(x + flat);
    float s0 = 0.f, s1 = 0.f, s2 = 0.f, s3 = 0.f;
    float l0 = 0.f, l1 = 0.f, l2 = 0.f, l3 = 0.f;
    for (int js = 0; js < JS; js++) {
        bf16x4_t ov = *(const bf16x4_t*)(Opart + (size_t)js * S + flat);
        s0 += (float)ov[0]; s1 += (float)ov[1];
        s2 += (float)ov[2]; s3 += (float)ov[3];
        float4 lv = *(const float4*)(lpart + (size_t)(js * B_ + b) * HW_ + n);
        l0 += lv.x; l1 += lv.y; l2 += lv.z; l3 += lv.w;
    }
    float4 r;
    r.x = xv.x + a * s0 / l0;
    r.y = xv.y + a * s1 / l1;
    r.z = xv.z + a * s2 / l2;
    r.w = xv.w + a * s3 / l3;
    *(float4*)(out + flat) = r;
}

// ---------------------------------------------------------------------------
extern "C" void kernel_launch(void* const* d_in, const int* in_sizes, int n_in,
                              void* d_out, int out_size, void* d_ws, size_t ws_size,
                              hipStream_t stream)
{
    (void)in_sizes; (void)n_in; (void)out_size;
    const float* x     = (const float*)d_in[0];
    const float* token = (const float*)d_in[1];
    const float* Wq    = (const float*)d_in[2];
    const float* Wk    = (const float*)d_in[3];
    const float* Wv    = (const float*)d_in[4];
    const float* alpha = (const float*)d_in[5];
    float* out = (float*)d_out;

    const size_t S = (size_t)B_ * HW_ * C_;   // 4,718,592 elements

    int JS = 4;
    for (;;) {
        size_t need = (12 + 2 * (size_t)JS) * S
                    + (size_t)JS * B_ * HW_ * 4 + (size_t)B_ * HW_ * 4;
        if (need <= ws_size || JS == 1) break;
        JS >>= 1;
    }
    const int tilesPerSplit = (HW_ / 32) / JS;

    char* ws = (char*)d_ws;
    bf16_t* qb    = (bf16_t*)(ws);               // [b][n][C]   bf16 (2S bytes @0)
    bf16_t* kb    = (bf16_t*)(ws + 2 * S);       // [b][n][C]   bf16
    bf16_t* vb    = (bf16_t*)(ws + 4 * S);       // [b][C][n]   bf16
    bf16_t* Wqb   = (bf16_t*)(ws + 6 * S);       // 128 KB
    bf16_t* Wkb   = Wqb + (size_t)C_ * C_;       // 256 KB
    bf16_t* Wvb   = Wkb + (size_t)C_ * TC_;      // 256 KB
    u8*     q8    = (u8*)(ws + 7 * S);           // fp8 [b][n][C]
    u8*     k8    = (u8*)(ws + 8 * S);           // fp8 [b][n][C]
    u8*     v8    = (u8*)(ws + 9 * S);           // fp8 [b][C][n]
    bf16_t* Opart = (bf16_t*)(ws + 12 * S);      // [js][b][c][n] bf16
    float*  lpart = (float*)(ws + (12 + 2 * (size_t)JS) * S);

    wcast_kernel<<<dim3(320), dim3(256), 0, stream>>>(Wq, Wk, Wv, Wqb, Wkb, Wvb);
    convqkv_kernel<C_,  false><<<dim3(HW_ / 16, B_), dim3(256), 0, stream>>>(x,     Wqb, nullptr, qb, nullptr);
    convqkv_kernel<TC_, true ><<<dim3(HW_ / 16, B_), dim3(256), 0, stream>>>(token, Wkb, Wvb,     kb, vb);
    // qb|kb|vb are contiguous 3S bf16 elements at ws+0 -> fp8 at ws+7S
    repack8_kernel<<<dim3(6912), dim3(256), 0, stream>>>((const bf16_t*)ws, q8);
    attn_part_kernel<<<dim3(HW_ / 128, JS, B_), dim3(256), 0, stream>>>(q8, k8, v8, Opart, lpart, tilesPerSplit);
    epilogue_kernel<<<dim3((int)(S / 1024)), dim3(256), 0, stream>>>(x, Opart, lpart, alpha, out, JS);
}

// Round 7
// 301.486 us; speedup vs baseline: 2.6022x; 1.0294x over previous
//
#include <hip/hip_runtime.h>

#define B_   8
#define C_   256
#define TC_  512
#define HW_  2304   // 48*48
#define EPS_ 1e-6f

typedef __bf16 bf16_t;
typedef __bf16 bf16x8 __attribute__((ext_vector_type(8)));
typedef __bf16 bf16x4_t __attribute__((ext_vector_type(4)));
typedef float  f32x4 __attribute__((ext_vector_type(4)));
typedef unsigned int  u32;
typedef unsigned int  u32x2 __attribute__((ext_vector_type(2)));
typedef unsigned int  u32x4 __attribute__((ext_vector_type(4)));
typedef long long     i64;
typedef unsigned char u8;

// async 16B global->LDS; lds dest is wave-uniform base (lane i -> base+16i)
__device__ __forceinline__ void g2l16(const void* g, void* l) {
    __builtin_amdgcn_global_load_lds(
        (const __attribute__((address_space(1))) unsigned int*)g,
        (__attribute__((address_space(3))) unsigned int*)l, 16, 0, 0);
}

__device__ __forceinline__ u8 to_fp8(float v) {
    return (u8)(__builtin_amdgcn_cvt_pk_fp8_f32(v, v, 0, false) & 0xff);
}

// ---------------------------------------------------------------------------
// Cast Wq|Wk|Wv fp32 -> bf16.
// ---------------------------------------------------------------------------
__global__ __launch_bounds__(256)
void wcast_kernel(const float* __restrict__ wq, const float* __restrict__ wk,
                  const float* __restrict__ wv,
                  bf16_t* __restrict__ oq, bf16_t* __restrict__ ok,
                  bf16_t* __restrict__ ov)
{
    int i4 = (blockIdx.x * 256 + threadIdx.x) * 4;
    const float* src; bf16_t* dst; int off;
    if (i4 < 65536)       { src = wq; dst = oq; off = i4; }
    else if (i4 < 196608) { src = wk; dst = ok; off = i4 - 65536; }
    else                  { src = wv; dst = ov; off = i4 - 196608; }
    float4 v = *(const float4*)(src + off);
    bf16x4_t o;
    o[0] = (__bf16)v.x; o[1] = (__bf16)v.y; o[2] = (__bf16)v.z; o[3] = (__bf16)v.w;
    *(bf16x4_t*)(dst + off) = o;
}

// ---------------------------------------------------------------------------
// Fused 1x1-conv stage, o-split, fp8 direct output, XCD-affine 1D grid.
// bid: b = bid&7 (one batch per XCD), n0 = (bid>>3)*16.
// Wave wv owns o-tiles [wv*4, wv*4+3] of K-GEMM and (if DO_V) V-GEMM.
// outA fp8 [b][n][C] = normalize_o(Wa X); outV fp8 [b][o][n] = Wv X.
// ---------------------------------------------------------------------------
template<int CIN, bool DO_V>
__global__ __launch_bounds__(256, 4)
void convqkv_kernel(const float* __restrict__ X, const bf16_t* __restrict__ Wa,
                    const bf16_t* __restrict__ Wvp, u8* __restrict__ outA,
                    u8* __restrict__ outV)
{
    const int bid = blockIdx.x;
    const int b  = bid & 7;
    const int n0 = (bid >> 3) * 16;
    const int tid = threadIdx.x;
    const int wv = tid >> 6;
    const int lane = tid & 63;
    const int quad = lane >> 4, l16 = lane & 15;

    __shared__ bf16_t T[16][CIN + 8];
    __shared__ float ssp[4][16];

    // ---- stage: fp32 [c][n] -> bf16 T[n][c] ----
    {
        const float* Xb = X + (size_t)b * CIN * HW_ + n0;
        const int cl = tid >> 2;          // 0..63
        const int n4 = (tid & 3) * 4;     // 0,4,8,12
#pragma unroll
        for (int cp = 0; cp < CIN; cp += 64) {
            float4 v = *(const float4*)(Xb + (size_t)(cp + cl) * HW_ + n4);
            T[n4 + 0][cp + cl] = (__bf16)v.x;
            T[n4 + 1][cp + cl] = (__bf16)v.y;
            T[n4 + 2][cp + cl] = (__bf16)v.z;
            T[n4 + 3][cp + cl] = (__bf16)v.w;
        }
    }
    __syncthreads();

    // ---- all 16 px rows into registers ----
    bf16x8 af[CIN / 32];
#pragma unroll
    for (int ks = 0; ks < CIN / 32; ks++)
        af[ks] = *(const bf16x8*)(&T[l16][ks * 32 + quad * 8]);

    const int ot0 = wv * 4;

    // ---- K-GEMM (ks outer, p inner: dep-chain distance 4) ----
    f32x4 accK[4];
#pragma unroll
    for (int p = 0; p < 4; p++) accK[p] = (f32x4){0.f, 0.f, 0.f, 0.f};
    {
        const bf16_t* wr[4];
#pragma unroll
        for (int p = 0; p < 4; p++)
            wr[p] = Wa + (size_t)((ot0 + p) * 16 + l16) * CIN + quad * 8;
#pragma unroll
        for (int ks = 0; ks < CIN / 32; ks++)
#pragma unroll
            for (int p = 0; p < 4; p++) {
                bf16x8 bw = *(const bf16x8*)(wr[p] + ks * 32);
                accK[p] = __builtin_amdgcn_mfma_f32_16x16x32_bf16(af[ks], bw, accK[p], 0, 0, 0);
            }
    }

    // ---- per-wave partial sum of squares over this wave's 64 o ----
    {
        float ssr[4];
#pragma unroll
        for (int r = 0; r < 4; r++) {
            float ss = accK[0][r] * accK[0][r] + accK[1][r] * accK[1][r]
                     + accK[2][r] * accK[2][r] + accK[3][r] * accK[3][r];
            ss += __shfl_xor(ss, 1);
            ss += __shfl_xor(ss, 2);
            ss += __shfl_xor(ss, 4);
            ss += __shfl_xor(ss, 8);
            ssr[r] = ss;
        }
        if (l16 == 0) {
#pragma unroll
            for (int r = 0; r < 4; r++) ssp[wv][quad * 4 + r] = ssr[r];
        }
    }

    // ---- V-GEMM (hides the ssp barrier) ----
    f32x4 accV[4];
    if (DO_V) {
#pragma unroll
        for (int p = 0; p < 4; p++) accV[p] = (f32x4){0.f, 0.f, 0.f, 0.f};
        const bf16_t* wr[4];
#pragma unroll
        for (int p = 0; p < 4; p++)
            wr[p] = Wvp + (size_t)((ot0 + p) * 16 + l16) * CIN + quad * 8;
#pragma unroll
        for (int ks = 0; ks < CIN / 32; ks++)
#pragma unroll
            for (int p = 0; p < 4; p++) {
                bf16x8 aw = *(const bf16x8*)(wr[p] + ks * 32);
                accV[p] = __builtin_amdgcn_mfma_f32_16x16x32_bf16(aw, af[ks], accV[p], 0, 0, 0);
            }
    }

    __syncthreads();

    // ---- combine norm partials, scale, write fp8 q/k ----
    float scale[4];
#pragma unroll
    for (int r = 0; r < 4; r++) {
        int px = quad * 4 + r;
        float s = ssp[0][px] + ssp[1][px] + ssp[2][px] + ssp[3][px];
        scale[r] = 1.0f / fmaxf(sqrtf(s), EPS_);
    }
    {
        // row = px = quad*4+r, col = o = (ot0+p)*16 + l16
        u8* oa = outA + ((size_t)b * HW_ + n0 + quad * 4) * C_ + l16;
#pragma unroll
        for (int p = 0; p < 4; p++)
#pragma unroll
            for (int r = 0; r < 4; r++)
                oa[(size_t)r * C_ + (ot0 + p) * 16] = to_fp8(accK[p][r] * scale[r]);
    }

    if (DO_V) {
        // row = o = (ot0+p)*16 + quad*4 + r, col = px = n0 + l16
#pragma unroll
        for (int p = 0; p < 4; p++)
#pragma unroll
            for (int r = 0; r < 4; r++)
                outV[((size_t)b * C_ + (ot0 + p) * 16 + quad * 4 + r) * HW_ + n0 + l16]
                    = to_fp8(accV[p][r]);
    }
}

// ---------------------------------------------------------------------------
// Attention partials, fp8 operands / fp32 accum, XCD-affine 1D grid:
// b = bid&7, r = bid>>3, js = r%JS, mt = r/JS.
// ---------------------------------------------------------------------------
__global__ __launch_bounds__(256, 2)
void attn_part_kernel(const u8* __restrict__ q8, const u8* __restrict__ k8,
                      const u8* __restrict__ v8,
                      bf16_t* __restrict__ Opart, float* __restrict__ lpart,
                      int tilesPerSplit, int JS)
{
    const int bid = blockIdx.x;
    const int b   = bid & 7;
    const int rr  = bid >> 3;
    const int js  = rr % JS;
    const int mt  = rr / JS;
    const int wv   = threadIdx.x >> 6;
    const int lane = threadIdx.x & 63;
    const int quad = lane >> 4;
    const int l16  = lane & 15;
    const int row0 = mt * 128 + wv * 32;
    const int jbase = js * tilesPerSplit * 32;

    const u8* qb = q8 + (size_t)b * HW_ * C_;
    const u8* kb = k8 + (size_t)b * HW_ * C_;
    const u8* vb = v8 + (size_t)b * C_ * HW_;

    __shared__ u8 Kbuf[2][8192];
    __shared__ u8 Vbuf[2][8192];
    __shared__ u8 Pt[4][1536];

    i64 aq0[8], aq1[8];
    {
        const u8* r0 = qb + (size_t)(row0 + l16) * C_ + quad * 8;
        const u8* r1 = r0 + 16 * C_;
#pragma unroll
        for (int t = 0; t < 8; t++) {
            aq0[t] = *(const i64*)(r0 + t * 32);
            aq1[t] = *(const i64*)(r1 + t * 32);
        }
    }

    f32x4 O0[16], O1[16];
#pragma unroll
    for (int i = 0; i < 16; i++) {
        O0[i] = (f32x4){0.f, 0.f, 0.f, 0.f};
        O1[i] = (f32x4){0.f, 0.f, 0.f, 0.f};
    }
    float lsum0[4] = {0.f, 0.f, 0.f, 0.f};
    float lsum1[4] = {0.f, 0.f, 0.f, 0.f};

    const int kj = lane & 31;
    const int kh = lane >> 5;
    const int vg = lane & 1;
    const int vc = lane >> 1;

#define STAGE(bufi, j0g)                                                       \
    {                                                                          \
        _Pragma("unroll")                                                      \
        for (int p = 0; p < 2; p++) {                                          \
            int i = wv * 2 + p;                                                \
            int s = i * 2 + kh;                                                \
            g2l16(kb + (size_t)((j0g) + kj) * C_ + s * 16,                     \
                  &Kbuf[bufi][i * 1024]);                                      \
        }                                                                      \
        _Pragma("unroll")                                                      \
        for (int p = 0; p < 2; p++) {                                          \
            int i = wv * 2 + p;                                                \
            int c = i * 32 + vc;                                               \
            g2l16(vb + (size_t)c * HW_ + (j0g) + vg * 16,                      \
                  &Vbuf[bufi][i * 1024]);                                      \
        }                                                                      \
    }

    STAGE(0, jbase)

    u8* pw = &Pt[wv][0];
    const int koff = (quad >> 1) * 512 + l16 * 16 + (quad & 1) * 8;
    const u32 sel = (quad < 2) ? 0x06040200u : 0x07050301u;

    for (int tt = 0; tt < tilesPerSplit; tt++) {
        __syncthreads();
        if (tt + 1 < tilesPerSplit) STAGE((tt + 1) & 1, jbase + (tt + 1) * 32)

        const u8* Kb = Kbuf[tt & 1];
        const u8* Vb = Vbuf[tt & 1];

        f32x4 s00 = (f32x4){0.f,0.f,0.f,0.f}, s01 = (f32x4){0.f,0.f,0.f,0.f};
        f32x4 s10 = (f32x4){0.f,0.f,0.f,0.f}, s11 = (f32x4){0.f,0.f,0.f,0.f};
#pragma unroll
        for (int t = 0; t < 8; t++) {
            i64 bk0 = *(const i64*)(Kb + t * 1024 + koff);
            i64 bk1 = *(const i64*)(Kb + t * 1024 + koff + 256);
            s00 = __builtin_amdgcn_mfma_f32_16x16x32_fp8_fp8(aq0[t], bk0, s00, 0, 0, 0);
            s01 = __builtin_amdgcn_mfma_f32_16x16x32_fp8_fp8(aq0[t], bk1, s01, 0, 0, 0);
            s10 = __builtin_amdgcn_mfma_f32_16x16x32_fp8_fp8(aq1[t], bk0, s10, 0, 0, 0);
            s11 = __builtin_amdgcn_mfma_f32_16x16x32_fp8_fp8(aq1[t], bk1, s11, 0, 0, 0);
        }
#pragma unroll
        for (int r = 0; r < 4; r++) {
            float p00 = __expf(s00[r] * 0.0625f), p01 = __expf(s01[r] * 0.0625f);
            float p10 = __expf(s10[r] * 0.0625f), p11 = __expf(s11[r] * 0.0625f);
            lsum0[r] += p00 + p01;
            lsum1[r] += p10 + p11;
            u32 w0 = __builtin_amdgcn_cvt_pk_fp8_f32(p00, p01, 0, false);
            u32 w1 = __builtin_amdgcn_cvt_pk_fp8_f32(p10, p11, 0, false);
            int ro = (quad * 4 + r) * 48 + l16 * 2;
            *(short*)(pw + ro)       = (short)w0;
            *(short*)(pw + 768 + ro) = (short)w1;
        }
        i64 ap0, ap1;
        {
            u32x4 d = *(const u32x4*)(pw + l16 * 48 + (quad & 1) * 16);
            u32 lo = __builtin_amdgcn_perm(d[1], d[0], sel);
            u32 hi = __builtin_amdgcn_perm(d[3], d[2], sel);
            ap0 = ((i64)hi << 32) | (i64)lo;
            u32x4 e = *(const u32x4*)(pw + 768 + l16 * 48 + (quad & 1) * 16);
            lo = __builtin_amdgcn_perm(e[1], e[0], sel);
            hi = __builtin_amdgcn_perm(e[3], e[2], sel);
            ap1 = ((i64)hi << 32) | (i64)lo;
        }
#pragma unroll
        for (int ct = 0; ct < 16; ct++) {
            i64 bv = *(const i64*)(Vb + ct * 512 + l16 * 32 + quad * 8);
            O0[ct] = __builtin_amdgcn_mfma_f32_16x16x32_fp8_fp8(ap0, bv, O0[ct], 0, 0, 0);
            O1[ct] = __builtin_amdgcn_mfma_f32_16x16x32_fp8_fp8(ap1, bv, O1[ct], 0, 0, 0);
        }
    }

#pragma unroll
    for (int r = 0; r < 4; r++) {
        float t0 = lsum0[r], t1 = lsum1[r];
        t0 += __shfl_xor(t0, 1); t0 += __shfl_xor(t0, 2);
        t0 += __shfl_xor(t0, 4); t0 += __shfl_xor(t0, 8);
        t1 += __shfl_xor(t1, 1); t1 += __shfl_xor(t1, 2);
        t1 += __shfl_xor(t1, 4); t1 += __shfl_xor(t1, 8);
        lsum0[r] = t0; lsum1[r] = t1;
    }
    float* lp = lpart + (size_t)(js * B_ + b) * HW_;
    if (l16 == 0) {
        float4 a0; a0.x = lsum0[0]; a0.y = lsum0[1]; a0.z = lsum0[2]; a0.w = lsum0[3];
        float4 a1; a1.x = lsum1[0]; a1.y = lsum1[1]; a1.z = lsum1[2]; a1.w = lsum1[3];
        *(float4*)(lp + row0 + quad * 4)      = a0;
        *(float4*)(lp + row0 + 16 + quad * 4) = a1;
    }
    bf16_t* op = Opart + (size_t)(js * B_ + b) * C_ * HW_;
#pragma unroll
    for (int ct = 0; ct < 16; ct++) {
        int c = ct * 16 + l16;
        bf16x4_t v0, v1;
        v0[0] = (__bf16)O0[ct][0]; v0[1] = (__bf16)O0[ct][1];
        v0[2] = (__bf16)O0[ct][2]; v0[3] = (__bf16)O0[ct][3];
        v1[0] = (__bf16)O1[ct][0]; v1[1] = (__bf16)O1[ct][1];
        v1[2] = (__bf16)O1[ct][2]; v1[3] = (__bf16)O1[ct][3];
        *(bf16x4_t*)(op + (size_t)c * HW_ + row0 + quad * 4)      = v0;
        *(bf16x4_t*)(op + (size_t)c * HW_ + row0 + 16 + quad * 4) = v1;
    }
#undef STAGE
}

// ---------------------------------------------------------------------------
// out[b][c][n] = x + alpha * (sum_js Opart) / (sum_js lpart[b][n])
// ---------------------------------------------------------------------------
__global__ __launch_bounds__(256)
void epilogue_kernel(const float* __restrict__ x, const bf16_t* __restrict__ Opart,
                     const float* __restrict__ lpart, const float* __restrict__ alphaPtr,
                     float* __restrict__ out, int JS)
{
    const float a = *alphaPtr;
    const size_t S = (size_t)B_ * C_ * HW_;
    size_t flat = ((size_t)blockIdx.x * 256 + threadIdx.x) * 4;
    int bc = (int)(flat / HW_);
    int n  = (int)(flat % HW_);
    int b  = bc >> 8;
    float4 xv = *(const float4*)(x + flat);
    float s0 = 0.f, s1 = 0.f, s2 = 0.f, s3 = 0.f;
    float l0 = 0.f, l1 = 0.f, l2 = 0.f, l3 = 0.f;
    for (int js = 0; js < JS; js++) {
        bf16x4_t ov = *(const bf16x4_t*)(Opart + (size_t)js * S + flat);
        s0 += (float)ov[0]; s1 += (float)ov[1];
        s2 += (float)ov[2]; s3 += (float)ov[3];
        float4 lv = *(const float4*)(lpart + (size_t)(js * B_ + b) * HW_ + n);
        l0 += lv.x; l1 += lv.y; l2 += lv.z; l3 += lv.w;
    }
    float4 r;
    r.x = xv.x + a * s0 / l0;
    r.y = xv.y + a * s1 / l1;
    r.z = xv.z + a * s2 / l2;
    r.w = xv.w + a * s3 / l3;
    *(float4*)(out + flat) = r;
}

// ---------------------------------------------------------------------------
extern "C" void kernel_launch(void* const* d_in, const int* in_sizes, int n_in,
                              void* d_out, int out_size, void* d_ws, size_t ws_size,
                              hipStream_t stream)
{
    (void)in_sizes; (void)n_in; (void)out_size;
    const float* x     = (const float*)d_in[0];
    const float* token = (const float*)d_in[1];
    const float* Wq    = (const float*)d_in[2];
    const float* Wk    = (const float*)d_in[3];
    const float* Wv    = (const float*)d_in[4];
    const float* alpha = (const float*)d_in[5];
    float* out = (float*)d_out;

    const size_t S = (size_t)B_ * HW_ * C_;   // 4,718,592 elements

    int JS = 8;
    for (;;) {
        size_t need = (12 + 2 * (size_t)JS) * S
                    + (size_t)JS * B_ * HW_ * 4 + (size_t)B_ * HW_ * 4;
        if (need <= ws_size || JS == 1) break;
        JS >>= 1;
    }
    const int tilesPerSplit = (HW_ / 32) / JS;  // 72/JS

    char* ws = (char*)d_ws;
    bf16_t* Wqb   = (bf16_t*)(ws + 6 * S);       // 128 KB
    bf16_t* Wkb   = Wqb + (size_t)C_ * C_;       // 256 KB
    bf16_t* Wvb   = Wkb + (size_t)C_ * TC_;      // 256 KB
    u8*     q8    = (u8*)(ws + 7 * S);           // fp8 [b][n][C]
    u8*     k8    = (u8*)(ws + 8 * S);           // fp8 [b][n][C]
    u8*     v8    = (u8*)(ws + 9 * S);           // fp8 [b][C][n]
    bf16_t* Opart = (bf16_t*)(ws + 12 * S);      // [js][b][c][n] bf16
    float*  lpart = (float*)(ws + (12 + 2 * (size_t)JS) * S);

    wcast_kernel<<<dim3(320), dim3(256), 0, stream>>>(Wq, Wk, Wv, Wqb, Wkb, Wvb);
    convqkv_kernel<C_,  false><<<dim3(B_ * HW_ / 16), dim3(256), 0, stream>>>(x,     Wqb, nullptr, q8, nullptr);
    convqkv_kernel<TC_, true ><<<dim3(B_ * HW_ / 16), dim3(256), 0, stream>>>(token, Wkb, Wvb,     k8, v8);
    attn_part_kernel<<<dim3(JS * B_ * (HW_ / 128)), dim3(256), 0, stream>>>(q8, k8, v8, Opart, lpart, tilesPerSplit, JS);
    epilogue_kernel<<<dim3((int)(S / 1024)), dim3(256), 0, stream>>>(x, Opart, lpart, alpha, out, JS);
}

// Round 8
// 242.634 us; speedup vs baseline: 3.2334x; 1.2426x over previous
//
#include <hip/hip_runtime.h>

#define B_   8
#define C_   256
#define TC_  512
#define HW_  2304   // 48*48
#define EPS_ 1e-6f

typedef __bf16 bf16_t;
typedef __bf16 bf16x8 __attribute__((ext_vector_type(8)));
typedef __bf16 bf16x4_t __attribute__((ext_vector_type(4)));
typedef float  f32x4 __attribute__((ext_vector_type(4)));
typedef unsigned int  u32;
typedef unsigned int  u32x2 __attribute__((ext_vector_type(2)));
typedef unsigned int  u32x4 __attribute__((ext_vector_type(4)));
typedef long long     i64;
typedef unsigned char u8;

// async 16B global->LDS; lds dest is wave-uniform base (lane i -> base+16i)
__device__ __forceinline__ void g2l16(const void* g, void* l) {
    __builtin_amdgcn_global_load_lds(
        (const __attribute__((address_space(1))) unsigned int*)g,
        (__attribute__((address_space(3))) unsigned int*)l, 16, 0, 0);
}

__device__ __forceinline__ u8 to_fp8(float v) {
    return (u8)(__builtin_amdgcn_cvt_pk_fp8_f32(v, v, 0, false) & 0xff);
}

// ---------------------------------------------------------------------------
// W -> fragment-major bf16.  For frag f=(ot,ks) of matrix W[CO][CIN], lane l
// (l16=l&15, quad=l>>4) owns W[(ot*16+l16)*CIN + ks*32 + quad*8 .. +8).
// Output: Wlin[f*512 + l*8]  (512 bf16 = 1 KB per frag) -> the conv kernels
// load each frag as ONE coalesced 1-KB wave read instead of 16 scattered
// 64-B lines.  Layout identical for B-operand (K-GEMM) and A-operand (V-GEMM).
// Frags: Wq 16x8=128 | Wk 16x16=256 | Wv 16x16=256.  One frag per wave.
// ---------------------------------------------------------------------------
__global__ __launch_bounds__(256)
void wfrag_kernel(const float* __restrict__ wq, const float* __restrict__ wk,
                  const float* __restrict__ wv,
                  bf16_t* __restrict__ oq, bf16_t* __restrict__ ok,
                  bf16_t* __restrict__ ov)
{
    const int fid = blockIdx.x * 4 + (threadIdx.x >> 6);   // 0..639
    const int lane = threadIdx.x & 63;
    const int l16 = lane & 15, quad = lane >> 4;

    const float* src; bf16_t* dst; int cin, f;
    if (fid < 128)      { src = wq; dst = oq; cin = C_;  f = fid; }
    else if (fid < 384) { src = wk; dst = ok; cin = TC_; f = fid - 128; }
    else                { src = wv; dst = ov; cin = TC_; f = fid - 384; }
    const int nks = cin / 32;
    const int ot = f / nks, ks = f % nks;

    const float* s = src + (size_t)(ot * 16 + l16) * cin + ks * 32 + quad * 8;
    float4 a = *(const float4*)(s);
    float4 b = *(const float4*)(s + 4);
    bf16x8 o;
    o[0] = (__bf16)a.x; o[1] = (__bf16)a.y; o[2] = (__bf16)a.z; o[3] = (__bf16)a.w;
    o[4] = (__bf16)b.x; o[5] = (__bf16)b.y; o[6] = (__bf16)b.z; o[7] = (__bf16)b.w;
    *(bf16x8*)(dst + (size_t)f * 512 + lane * 8) = o;
}

// ---------------------------------------------------------------------------
// Fused 1x1-conv stage, o-split, fp8 direct output, frag-major W.
// bid: b = bid&7 (XCD affinity), n0 = (bid>>3)*16.
// Wave wv owns o-tiles [wv*4, wv*4+3] of K-GEMM and (if DO_V) V-GEMM.
// W frag (ot,ks) load: Wlin + (ot*nks+ks)*512 + lane*8  -> coalesced 1 KB.
// outA fp8 [b][n][C] = normalize_o(Wa X); outV fp8 [b][o][n] = Wv X.
// ---------------------------------------------------------------------------
template<int CIN, bool DO_V>
__global__ __launch_bounds__(256, 4)
void convqkv_kernel(const float* __restrict__ X, const bf16_t* __restrict__ Wa,
                    const bf16_t* __restrict__ Wvp, u8* __restrict__ outA,
                    u8* __restrict__ outV)
{
    const int bid = blockIdx.x;
    const int b  = bid & 7;
    const int n0 = (bid >> 3) * 16;
    const int tid = threadIdx.x;
    const int wv = tid >> 6;
    const int lane = tid & 63;
    const int quad = lane >> 4, l16 = lane & 15;
    const int NKS = CIN / 32;

    __shared__ bf16_t T[16][CIN + 8];
    __shared__ float ssp[4][16];

    // ---- stage: fp32 [c][n] -> bf16 T[n][c] ----
    {
        const float* Xb = X + (size_t)b * CIN * HW_ + n0;
        const int cl = tid >> 2;          // 0..63
        const int n4 = (tid & 3) * 4;     // 0,4,8,12
#pragma unroll
        for (int cp = 0; cp < CIN; cp += 64) {
            float4 v = *(const float4*)(Xb + (size_t)(cp + cl) * HW_ + n4);
            T[n4 + 0][cp + cl] = (__bf16)v.x;
            T[n4 + 1][cp + cl] = (__bf16)v.y;
            T[n4 + 2][cp + cl] = (__bf16)v.z;
            T[n4 + 3][cp + cl] = (__bf16)v.w;
        }
    }
    __syncthreads();

    // ---- all 16 px rows into registers ----
    bf16x8 af[CIN / 32];
#pragma unroll
    for (int ks = 0; ks < CIN / 32; ks++)
        af[ks] = *(const bf16x8*)(&T[l16][ks * 32 + quad * 8]);

    const int ot0 = wv * 4;

    // ---- K-GEMM (ks outer, p inner; coalesced frag loads) ----
    f32x4 accK[4];
#pragma unroll
    for (int p = 0; p < 4; p++) accK[p] = (f32x4){0.f, 0.f, 0.f, 0.f};
    {
        const bf16_t* wbase = Wa + ((size_t)ot0 * NKS) * 512 + lane * 8;
#pragma unroll
        for (int ks = 0; ks < CIN / 32; ks++)
#pragma unroll
            for (int p = 0; p < 4; p++) {
                bf16x8 bw = *(const bf16x8*)(wbase + (size_t)(p * NKS + ks) * 512);
                accK[p] = __builtin_amdgcn_mfma_f32_16x16x32_bf16(af[ks], bw, accK[p], 0, 0, 0);
            }
    }

    // ---- per-wave partial sum of squares over this wave's 64 o ----
    {
        float ssr[4];
#pragma unroll
        for (int r = 0; r < 4; r++) {
            float ss = accK[0][r] * accK[0][r] + accK[1][r] * accK[1][r]
                     + accK[2][r] * accK[2][r] + accK[3][r] * accK[3][r];
            ss += __shfl_xor(ss, 1);
            ss += __shfl_xor(ss, 2);
            ss += __shfl_xor(ss, 4);
            ss += __shfl_xor(ss, 8);
            ssr[r] = ss;
        }
        if (l16 == 0) {
#pragma unroll
            for (int r = 0; r < 4; r++) ssp[wv][quad * 4 + r] = ssr[r];
        }
    }

    // ---- V-GEMM (hides the ssp barrier) ----
    f32x4 accV[4];
    if (DO_V) {
#pragma unroll
        for (int p = 0; p < 4; p++) accV[p] = (f32x4){0.f, 0.f, 0.f, 0.f};
        const bf16_t* wbase = Wvp + ((size_t)ot0 * NKS) * 512 + lane * 8;
#pragma unroll
        for (int ks = 0; ks < CIN / 32; ks++)
#pragma unroll
            for (int p = 0; p < 4; p++) {
                bf16x8 aw = *(const bf16x8*)(wbase + (size_t)(p * NKS + ks) * 512);
                accV[p] = __builtin_amdgcn_mfma_f32_16x16x32_bf16(aw, af[ks], accV[p], 0, 0, 0);
            }
    }

    __syncthreads();

    // ---- combine norm partials, scale, write fp8 q/k ----
    float scale[4];
#pragma unroll
    for (int r = 0; r < 4; r++) {
        int px = quad * 4 + r;
        float s = ssp[0][px] + ssp[1][px] + ssp[2][px] + ssp[3][px];
        scale[r] = 1.0f / fmaxf(sqrtf(s), EPS_);
    }
    {
        // row = px = quad*4+r, col = o = (ot0+p)*16 + l16
        u8* oa = outA + ((size_t)b * HW_ + n0 + quad * 4) * C_ + l16;
#pragma unroll
        for (int p = 0; p < 4; p++)
#pragma unroll
            for (int r = 0; r < 4; r++)
                oa[(size_t)r * C_ + (ot0 + p) * 16] = to_fp8(accK[p][r] * scale[r]);
    }

    if (DO_V) {
        // row = o = (ot0+p)*16 + quad*4 + r, col = px = n0 + l16
#pragma unroll
        for (int p = 0; p < 4; p++)
#pragma unroll
            for (int r = 0; r < 4; r++)
                outV[((size_t)b * C_ + (ot0 + p) * 16 + quad * 4 + r) * HW_ + n0 + l16]
                    = to_fp8(accV[p][r]);
    }
}

// ---------------------------------------------------------------------------
// Attention partials, fp8 operands / fp32 accum, XCD-affine 1D grid:
// b = bid&7, r = bid>>3, js = r%JS, mt = r/JS.  (unchanged from round 7)
// ---------------------------------------------------------------------------
__global__ __launch_bounds__(256, 2)
void attn_part_kernel(const u8* __restrict__ q8, const u8* __restrict__ k8,
                      const u8* __restrict__ v8,
                      bf16_t* __restrict__ Opart, float* __restrict__ lpart,
                      int tilesPerSplit, int JS)
{
    const int bid = blockIdx.x;
    const int b   = bid & 7;
    const int rr  = bid >> 3;
    const int js  = rr % JS;
    const int mt  = rr / JS;
    const int wv   = threadIdx.x >> 6;
    const int lane = threadIdx.x & 63;
    const int quad = lane >> 4;
    const int l16  = lane & 15;
    const int row0 = mt * 128 + wv * 32;
    const int jbase = js * tilesPerSplit * 32;

    const u8* qb = q8 + (size_t)b * HW_ * C_;
    const u8* kb = k8 + (size_t)b * HW_ * C_;
    const u8* vb = v8 + (size_t)b * C_ * HW_;

    __shared__ u8 Kbuf[2][8192];
    __shared__ u8 Vbuf[2][8192];
    __shared__ u8 Pt[4][1536];

    i64 aq0[8], aq1[8];
    {
        const u8* r0 = qb + (size_t)(row0 + l16) * C_ + quad * 8;
        const u8* r1 = r0 + 16 * C_;
#pragma unroll
        for (int t = 0; t < 8; t++) {
            aq0[t] = *(const i64*)(r0 + t * 32);
            aq1[t] = *(const i64*)(r1 + t * 32);
        }
    }

    f32x4 O0[16], O1[16];
#pragma unroll
    for (int i = 0; i < 16; i++) {
        O0[i] = (f32x4){0.f, 0.f, 0.f, 0.f};
        O1[i] = (f32x4){0.f, 0.f, 0.f, 0.f};
    }
    float lsum0[4] = {0.f, 0.f, 0.f, 0.f};
    float lsum1[4] = {0.f, 0.f, 0.f, 0.f};

    const int kj = lane & 31;
    const int kh = lane >> 5;
    const int vg = lane & 1;
    const int vc = lane >> 1;

#define STAGE(bufi, j0g)                                                       \
    {                                                                          \
        _Pragma("unroll")                                                      \
        for (int p = 0; p < 2; p++) {                                          \
            int i = wv * 2 + p;                                                \
            int s = i * 2 + kh;                                                \
            g2l16(kb + (size_t)((j0g) + kj) * C_ + s * 16,                     \
                  &Kbuf[bufi][i * 1024]);                                      \
        }                                                                      \
        _Pragma("unroll")                                                      \
        for (int p = 0; p < 2; p++) {                                          \
            int i = wv * 2 + p;                                                \
            int c = i * 32 + vc;                                               \
            g2l16(vb + (size_t)c * HW_ + (j0g) + vg * 16,                      \
                  &Vbuf[bufi][i * 1024]);                                      \
        }                                                                      \
    }

    STAGE(0, jbase)

    u8* pw = &Pt[wv][0];
    const int koff = (quad >> 1) * 512 + l16 * 16 + (quad & 1) * 8;
    const u32 sel = (quad < 2) ? 0x06040200u : 0x07050301u;

    for (int tt = 0; tt < tilesPerSplit; tt++) {
        __syncthreads();
        if (tt + 1 < tilesPerSplit) STAGE((tt + 1) & 1, jbase + (tt + 1) * 32)

        const u8* Kb = Kbuf[tt & 1];
        const u8* Vb = Vbuf[tt & 1];

        f32x4 s00 = (f32x4){0.f,0.f,0.f,0.f}, s01 = (f32x4){0.f,0.f,0.f,0.f};
        f32x4 s10 = (f32x4){0.f,0.f,0.f,0.f}, s11 = (f32x4){0.f,0.f,0.f,0.f};
#pragma unroll
        for (int t = 0; t < 8; t++) {
            i64 bk0 = *(const i64*)(Kb + t * 1024 + koff);
            i64 bk1 = *(const i64*)(Kb + t * 1024 + koff + 256);
            s00 = __builtin_amdgcn_mfma_f32_16x16x32_fp8_fp8(aq0[t], bk0, s00, 0, 0, 0);
            s01 = __builtin_amdgcn_mfma_f32_16x16x32_fp8_fp8(aq0[t], bk1, s01, 0, 0, 0);
            s10 = __builtin_amdgcn_mfma_f32_16x16x32_fp8_fp8(aq1[t], bk0, s10, 0, 0, 0);
            s11 = __builtin_amdgcn_mfma_f32_16x16x32_fp8_fp8(aq1[t], bk1, s11, 0, 0, 0);
        }
#pragma unroll
        for (int r = 0; r < 4; r++) {
            float p00 = __expf(s00[r] * 0.0625f), p01 = __expf(s01[r] * 0.0625f);
            float p10 = __expf(s10[r] * 0.0625f), p11 = __expf(s11[r] * 0.0625f);
            lsum0[r] += p00 + p01;
            lsum1[r] += p10 + p11;
            u32 w0 = __builtin_amdgcn_cvt_pk_fp8_f32(p00, p01, 0, false);
            u32 w1 = __builtin_amdgcn_cvt_pk_fp8_f32(p10, p11, 0, false);
            int ro = (quad * 4 + r) * 48 + l16 * 2;
            *(short*)(pw + ro)       = (short)w0;
            *(short*)(pw + 768 + ro) = (short)w1;
        }
        i64 ap0, ap1;
        {
            u32x4 d = *(const u32x4*)(pw + l16 * 48 + (quad & 1) * 16);
            u32 lo = __builtin_amdgcn_perm(d[1], d[0], sel);
            u32 hi = __builtin_amdgcn_perm(d[3], d[2], sel);
            ap0 = ((i64)hi << 32) | (i64)lo;
            u32x4 e = *(const u32x4*)(pw + 768 + l16 * 48 + (quad & 1) * 16);
            lo = __builtin_amdgcn_perm(e[1], e[0], sel);
            hi = __builtin_amdgcn_perm(e[3], e[2], sel);
            ap1 = ((i64)hi << 32) | (i64)lo;
        }
#pragma unroll
        for (int ct = 0; ct < 16; ct++) {
            i64 bv = *(const i64*)(Vb + ct * 512 + l16 * 32 + quad * 8);
            O0[ct] = __builtin_amdgcn_mfma_f32_16x16x32_fp8_fp8(ap0, bv, O0[ct], 0, 0, 0);
            O1[ct] = __builtin_amdgcn_mfma_f32_16x16x32_fp8_fp8(ap1, bv, O1[ct], 0, 0, 0);
        }
    }

#pragma unroll
    for (int r = 0; r < 4; r++) {
        float t0 = lsum0[r], t1 = lsum1[r];
        t0 += __shfl_xor(t0, 1); t0 += __shfl_xor(t0, 2);
        t0 += __shfl_xor(t0, 4); t0 += __shfl_xor(t0, 8);
        t1 += __shfl_xor(t1, 1); t1 += __shfl_xor(t1, 2);
        t1 += __shfl_xor(t1, 4); t1 += __shfl_xor(t1, 8);
        lsum0[r] = t0; lsum1[r] = t1;
    }
    float* lp = lpart + (size_t)(js * B_ + b) * HW_;
    if (l16 == 0) {
        float4 a0; a0.x = lsum0[0]; a0.y = lsum0[1]; a0.z = lsum0[2]; a0.w = lsum0[3];
        float4 a1; a1.x = lsum1[0]; a1.y = lsum1[1]; a1.z = lsum1[2]; a1.w = lsum1[3];
        *(float4*)(lp + row0 + quad * 4)      = a0;
        *(float4*)(lp + row0 + 16 + quad * 4) = a1;
    }
    bf16_t* op = Opart + (size_t)(js * B_ + b) * C_ * HW_;
#pragma unroll
    for (int ct = 0; ct < 16; ct++) {
        int c = ct * 16 + l16;
        bf16x4_t v0, v1;
        v0[0] = (__bf16)O0[ct][0]; v0[1] = (__bf16)O0[ct][1];
        v0[2] = (__bf16)O0[ct][2]; v0[3] = (__bf16)O0[ct][3];
        v1[0] = (__bf16)O1[ct][0]; v1[1] = (__bf16)O1[ct][1];
        v1[2] = (__bf16)O1[ct][2]; v1[3] = (__bf16)O1[ct][3];
        *(bf16x4_t*)(op + (size_t)c * HW_ + row0 + quad * 4)      = v0;
        *(bf16x4_t*)(op + (size_t)c * HW_ + row0 + 16 + quad * 4) = v1;
    }
#undef STAGE
}

// ---------------------------------------------------------------------------
// out[b][c][n] = x + alpha * (sum_js Opart) / (sum_js lpart[b][n])
// ---------------------------------------------------------------------------
__global__ __launch_bounds__(256)
void epilogue_kernel(const float* __restrict__ x, const bf16_t* __restrict__ Opart,
                     const float* __restrict__ lpart, const float* __restrict__ alphaPtr,
                     float* __restrict__ out, int JS)
{
    const float a = *alphaPtr;
    const size_t S = (size_t)B_ * C_ * HW_;
    size_t flat = ((size_t)blockIdx.x * 256 + threadIdx.x) * 4;
    int bc = (int)(flat / HW_);
    int n  = (int)(flat % HW_);
    int b  = bc >> 8;
    float4 xv = *(const float4*)(x + flat);
    float s0 = 0.f, s1 = 0.f, s2 = 0.f, s3 = 0.f;
    float l0 = 0.f, l1 = 0.f, l2 = 0.f, l3 = 0.f;
    for (int js = 0; js < JS; js++) {
        bf16x4_t ov = *(const bf16x4_t*)(Opart + (size_t)js * S + flat);
        s0 += (float)ov[0]; s1 += (float)ov[1];
        s2 += (float)ov[2]; s3 += (float)ov[3];
        float4 lv = *(const float4*)(lpart + (size_t)(js * B_ + b) * HW_ + n);
        l0 += lv.x; l1 += lv.y; l2 += lv.z; l3 += lv.w;
    }
    float4 r;
    r.x = xv.x + a * s0 / l0;
    r.y = xv.y + a * s1 / l1;
    r.z = xv.z + a * s2 / l2;
    r.w = xv.w + a * s3 / l3;
    *(float4*)(out + flat) = r;
}

// ---------------------------------------------------------------------------
extern "C" void kernel_launch(void* const* d_in, const int* in_sizes, int n_in,
                              void* d_out, int out_size, void* d_ws, size_t ws_size,
                              hipStream_t stream)
{
    (void)in_sizes; (void)n_in; (void)out_size;
    const float* x     = (const float*)d_in[0];
    const float* token = (const float*)d_in[1];
    const float* Wq    = (const float*)d_in[2];
    const float* Wk    = (const float*)d_in[3];
    const float* Wv    = (const float*)d_in[4];
    const float* alpha = (const float*)d_in[5];
    float* out = (float*)d_out;

    const size_t S = (size_t)B_ * HW_ * C_;   // 4,718,592 elements

    int JS = 8;
    for (;;) {
        size_t need = (12 + 2 * (size_t)JS) * S
                    + (size_t)JS * B_ * HW_ * 4 + (size_t)B_ * HW_ * 4;
        if (need <= ws_size || JS == 1) break;
        JS >>= 1;
    }
    const int tilesPerSplit = (HW_ / 32) / JS;  // 72/JS

    char* ws = (char*)d_ws;
    bf16_t* WqL   = (bf16_t*)(ws + 6 * S);       // frag-major, 128 KB
    bf16_t* WkL   = WqL + (size_t)C_ * C_;       // frag-major, 256 KB
    bf16_t* WvL   = WkL + (size_t)C_ * TC_;      // frag-major, 256 KB
    u8*     q8    = (u8*)(ws + 7 * S);           // fp8 [b][n][C]
    u8*     k8    = (u8*)(ws + 8 * S);           // fp8 [b][n][C]
    u8*     v8    = (u8*)(ws + 9 * S);           // fp8 [b][C][n]
    bf16_t* Opart = (bf16_t*)(ws + 12 * S);      // [js][b][c][n] bf16
    float*  lpart = (float*)(ws + (12 + 2 * (size_t)JS) * S);

    wfrag_kernel<<<dim3(160), dim3(256), 0, stream>>>(Wq, Wk, Wv, WqL, WkL, WvL);
    convqkv_kernel<C_,  false><<<dim3(B_ * HW_ / 16), dim3(256), 0, stream>>>(x,     WqL, nullptr, q8, nullptr);
    convqkv_kernel<TC_, true ><<<dim3(B_ * HW_ / 16), dim3(256), 0, stream>>>(token, WkL, WvL,     k8, v8);
    attn_part_kernel<<<dim3(JS * B_ * (HW_ / 128)), dim3(256), 0, stream>>>(q8, k8, v8, Opart, lpart, tilesPerSplit, JS);
    epilogue_kernel<<<dim3((int)(S / 1024)), dim3(256), 0, stream>>>(x, Opart, lpart, alpha, out, JS);
}